// Round 11
// baseline (461.941 us; speedup 1.0000x reference)
//
#include <hip/hip_runtime.h>
#include <hip/hip_bf16.h>
#include <cstdint>
#include <cstddef>

#define TLEN 2048
#define NB 2
#define DMODEL 1024
#define NH 16
#define NDH 64

typedef unsigned short ushortT;
typedef short bf16x8 __attribute__((ext_vector_type(8)));
typedef float f32x16 __attribute__((ext_vector_type(16)));

__device__ __forceinline__ ushortT f2bf(float f) {
  union { float f; unsigned int u; } x{f};
  unsigned int r = x.u + 0x7fff + ((x.u >> 16) & 1);   // RNE
  return (ushortT)(r >> 16);
}
__device__ __forceinline__ unsigned int pk2(float lo, float hi) {
  return ((unsigned int)f2bf(hi) << 16) | (unsigned int)f2bf(lo);
}
__device__ __forceinline__ float bf2f(ushortT u) {
  union { unsigned int u; float f; } x;
  x.u = ((unsigned int)u) << 16;
  return x.f;
}

__device__ __forceinline__ void gld_lds16(const void* g, void* l) {
  __builtin_amdgcn_global_load_lds(
      (const __attribute__((address_space(1))) unsigned int*)g,
      (__attribute__((address_space(3))) unsigned int*)l, 16, 0, 0);
}

// ---------------------------------------------------------------------------
// fused prologue: all f32->bf16 converts + mask floats + rk_ext zero row
// ---------------------------------------------------------------------------

__global__ __launch_bounds__(256) void cvt_all(
    const float* __restrict__ w, const float* __restrict__ wqkv,
    const float* __restrict__ r, const float* __restrict__ wr,
    const float* __restrict__ wo, ushortT* __restrict__ w_bf,
    ushortT* __restrict__ wqkv_bf, ushortT* __restrict__ r_bf,
    ushortT* __restrict__ wr_bf, ushortT* __restrict__ wo_bf,
    const int* __restrict__ mask, float* __restrict__ mfl,
    ushortT* __restrict__ rkE) {
  const size_t N0 = 1048576, N1 = N0 + 786432, N2 = N1 + 524288,
               N3 = N2 + 262144, N4 = N3 + 262144;
  size_t i = (size_t)blockIdx.x * 256 + threadIdx.x;
  const float* src; ushortT* dst; size_t off;
  if (i < N0)      { src = w;    dst = w_bf;    off = i; }
  else if (i < N1) { src = wqkv; dst = wqkv_bf; off = i - N0; }
  else if (i < N2) { src = r;    dst = r_bf;    off = i - N1; }
  else if (i < N3) { src = wr;   dst = wr_bf;   off = i - N2; }
  else if (i < N4) { src = wo;   dst = wo_bf;   off = i - N3; }
  else {
    size_t k = i - N4;
    if (k < 512) {                       // mask floats: 4 j per thread
      int j = (int)k * 4;
#pragma unroll
      for (int s = 0; s < 4; ++s) {
        mfl[j + s]        = mask[(size_t)(j + s) * NB]     ? 0.f : 1.f;
        mfl[TLEN + j + s] = mask[(size_t)(j + s) * NB + 1] ? 0.f : 1.f;
      }
    } else if (k < 512 + 256) {          // rk_ext zero row per head
      int ii = (int)k - 512; int h = ii >> 4, c = ii & 15;
      ushort4 z; z.x = 0; z.y = 0; z.z = 0; z.w = 0;
      *reinterpret_cast<ushort4*>(rkE + ((size_t)h * 4096 + 2048) * NDH + c * 4) = z;
    }
    return;
  }
  float4 v = reinterpret_cast<const float4*>(src)[off];
  ushort4 o;
  o.x = f2bf(v.x); o.y = f2bf(v.y); o.z = f2bf(v.z); o.w = f2bf(v.w);
  reinterpret_cast<ushort4*>(dst)[off] = o;
}

// ---------------------------------------------------------------------------
// bf16 MFMA GEMM, K-loop pipelined: fragments to regs -> lgkmcnt -> barrier ->
// stage next K-tile (stays in flight over MFMA) -> MFMA -> vmcnt(0) -> barrier
// ---------------------------------------------------------------------------

template <typename Epi>
__global__ __launch_bounds__(256) void gemm_bf16(const ushortT* __restrict__ A,
                                                 const ushortT* __restrict__ B,
                                                 int K, Epi epi) {
  __shared__ ushortT Al[128 * 64];
  __shared__ ushortT Bl[128 * 64];
  const int tid = threadIdx.x;
  const int lane = tid & 63;
  const int wv = tid >> 6;
  const int wm = wv >> 1, wn = wv & 1;
  const int m0 = blockIdx.y * 128;
  const int n0 = blockIdx.x * 128;
  const int r32 = lane & 31;
  const int hh = lane >> 5;

  auto STAGE = [&](int k0) {
#pragma unroll
    for (int it = 0; it < 4; ++it) {
      int idx = it * 256 + tid;          // 1024 chunks of 16B
      int r = idx >> 3, c = idx & 7;
      int gcol = k0 + ((c ^ (r & 7)) << 3);
      gld_lds16(A + (size_t)(m0 + r) * K + gcol, Al + idx * 8);
      gld_lds16(B + (size_t)(n0 + r) * K + gcol, Bl + idx * 8);
    }
  };

  f32x16 acc[2][2];
#pragma unroll
  for (int i = 0; i < 2; ++i)
#pragma unroll
    for (int j = 0; j < 2; ++j)
#pragma unroll
      for (int e = 0; e < 16; ++e) acc[i][j][e] = 0.f;

  STAGE(0);
  asm volatile("s_waitcnt vmcnt(0)");
  __builtin_amdgcn_s_barrier();

  for (int k0 = 0; k0 < K; k0 += 64) {
    bf16x8 af[4][2], bfr[4][2];
#pragma unroll
    for (int kc = 0; kc < 4; ++kc) {
      int lc = kc * 2 + hh;              // logical 16B chunk in row
#pragma unroll
      for (int f = 0; f < 2; ++f) {
        int ar = wm * 64 + f * 32 + r32;
        af[kc][f] = *(const bf16x8*)(Al + ar * 64 + ((lc ^ (ar & 7)) << 3));
        int br = wn * 64 + f * 32 + r32;
        bfr[kc][f] = *(const bf16x8*)(Bl + br * 64 + ((lc ^ (br & 7)) << 3));
      }
    }
    asm volatile("s_waitcnt lgkmcnt(0)");
    __builtin_amdgcn_s_barrier();        // LDS free to overwrite

    if (k0 + 64 < K) STAGE(k0 + 64);     // in flight across the MFMAs

    __builtin_amdgcn_s_setprio(1);
#pragma unroll
    for (int kc = 0; kc < 4; ++kc)
#pragma unroll
      for (int i = 0; i < 2; ++i)
#pragma unroll
        for (int j = 0; j < 2; ++j)
          acc[i][j] = __builtin_amdgcn_mfma_f32_32x32x16_bf16(af[kc][i], bfr[kc][j],
                                                              acc[i][j], 0, 0, 0);
    __builtin_amdgcn_s_setprio(0);

    if (k0 + 64 < K) {
      asm volatile("s_waitcnt vmcnt(0)");
      __builtin_amdgcn_s_barrier();      // next tile visible
    }
  }

#pragma unroll
  for (int i = 0; i < 2; ++i)
#pragma unroll
    for (int j = 0; j < 2; ++j)
#pragma unroll
      for (int rg = 0; rg < 16; ++rg) {
        int m = m0 + wm * 64 + i * 32 + (rg & 3) + 8 * (rg >> 2) + 4 * hh;
        int n = n0 + wn * 64 + j * 32 + r32;
        epi.store(m, n, acc[i][j][rg]);
      }
}

struct EpiQKV {
  ushortT* qb; ushortT* kb; ushortT* vtb; const float* bias;
  __device__ void store(int m, int n, float val) const {
    int t = m >> 1, b = m & 1;
    int which = n >> 10;
    int h = (n >> 6) & (NH - 1);
    int dh = n & (NDH - 1);
    int bh = b * NH + h;
    if (which == 0)
      qb[((size_t)bh * TLEN + t) * NDH + dh] = f2bf(val + bias[(h << 6) | dh]);
    else if (which == 1)
      kb[((size_t)bh * TLEN + t) * NDH + dh] = f2bf(val);
    else
      vtb[((size_t)bh * NDH + dh) * TLEN + t] = f2bf(val);
  }
};

struct EpiRK {   // rk_ext: row m = rk[m] (m<=2047); row 2048 = 0 (cvt_all);
                 // row m = rk[m-2049] (m>=2049)
  ushortT* rkE;
  __device__ void store(int m, int n, float val) const {
    int h = n >> 6, dh = n & 63;
    ushortT v = f2bf(val);
    rkE[((size_t)h * 4096 + m) * NDH + dh] = v;
    if (m <= 2046)
      rkE[((size_t)h * 4096 + m + 2049) * NDH + dh] = v;
  }
};

struct EpiOut {
  float* out;
  __device__ void store(int m, int n, float val) const {
    out[(size_t)m * DMODEL + n] = val;
  }
};

// ---------------------------------------------------------------------------
// FAST attention, LDS-staged + pipelined + XCD-affine swizzle.
// Work item = (bh, qt). flat = by*32+bx; xcd = flat&7 (round-robin dispatch
// assumption, learn_hip m157/m192); XCD c owns bh in [4c,4c+4) x all 32
// q-tiles -> per-XCD K/V/rk_ext working set ~4MB, L2-resident. Bijective.
// Rest identical to R10 kernel.
// ---------------------------------------------------------------------------

__global__ __launch_bounds__(128) void attn_fast(
    const ushortT* __restrict__ qb, const ushortT* __restrict__ kb,
    const ushortT* __restrict__ vtb, const ushortT* __restrict__ rkE,
    const float* __restrict__ mfl, unsigned int* __restrict__ S,
    float* __restrict__ linv_g, ushortT* __restrict__ av_bf) {
  __shared__ float W[2][64][32];
  __shared__ ushortT KT[2048];   // [32 j][8 x 16B chunks], chunk c at c^(row&7)
  __shared__ ushortT VT[2048];   // [64 d][4 x 16B chunks], chunk c at c^(d&3)
  __shared__ ushortT RK[6144];   // [96 rows][8 chunks],    chunk c at c^(row&7)

  const int flat = blockIdx.y * 32 + blockIdx.x;
  const int xcd = flat & 7;
  const int idx = flat >> 3;             // 0..127
  const int bh = xcd * 4 + (idx >> 5);
  const int qt = idx & 31;

  const int b = bh >> 4, h = bh & 15;
  const int t = threadIdx.x >> 6;        // q-tile wave
  const int lane = threadIdx.x & 63;
  const int ql = lane & 31;
  const int hh = lane >> 5;
  const int Q0 = qt * 64;
  const int q0 = Q0 + 32 * t;
  const int qg = q0 + ql;

  const ushortT* Qbh = qb + (size_t)bh * TLEN * NDH;
  const ushortT* Kbh = kb + (size_t)bh * TLEN * NDH;
  const ushortT* Vbh = vtb + (size_t)bh * NDH * TLEN;
  const ushortT* Rh  = rkE + (size_t)h * 4096 * NDH;
  const float* mflb  = mfl + (size_t)b * TLEN;
  unsigned int* Sb   = S + (size_t)bh * (TLEN / 2) * TLEN;
  float (*Wp)[32] = W[t];

  auto STAGE = [&](int j0) {
    const int U = 1984 + j0 - Q0;        // in [0, 4000]; U+96 <= 4096
#pragma unroll
    for (int i = 0; i < 6; ++i) {        // RK: 6 insts/wave
      int ci = (t * 6 + i) * 64 + lane;
      int row = ci >> 3, c = ci & 7;
      gld_lds16(Rh + (size_t)(U + row) * NDH + ((c ^ (row & 7)) << 3), RK + ci * 8);
    }
#pragma unroll
    for (int i = 0; i < 2; ++i) {        // KT + VT: 2+2 insts/wave
      int ci = (t * 2 + i) * 64 + lane;
      int row = ci >> 3, c = ci & 7;
      gld_lds16(Kbh + (size_t)(j0 + row) * NDH + ((c ^ (row & 7)) << 3), KT + ci * 8);
      int d = ci >> 2, c2 = ci & 3;
      gld_lds16(Vbh + (size_t)d * TLEN + j0 + ((c2 ^ (d & 3)) << 3), VT + ci * 8);
    }
  };

  bf16x8 Qf[4], Qs[4];
  {
    int r2 = min(qg + 1, TLEN - 1);
#pragma unroll
    for (int c = 0; c < 4; ++c) {
      Qf[c] = *(const bf16x8*)(Qbh + (size_t)qg * NDH + c * 16 + hh * 8);
      Qs[c] = *(const bf16x8*)(Qbh + (size_t)r2 * NDH + c * 16 + hh * 8);
    }
  }

  f32x16 pacc0, pacc1;
#pragma unroll
  for (int i = 0; i < 16; ++i) { pacc0[i] = 0.f; pacc1[i] = 0.f; }
  float l_acc = 0.f;

  // prologue: stage chunk 0, full drain
  STAGE(0);
  asm volatile("s_waitcnt vmcnt(0)");
  __builtin_amdgcn_s_barrier();

  for (int j0 = 0; j0 < TLEN; j0 += 32) {
    // current-chunk mask loads (oldest VMEM after stores -> cheap wait at exp)
    float4 mf4[4];
#pragma unroll
    for (int g = 0; g < 4; ++g)
      mf4[g] = *(const float4*)(mflb + j0 + 8 * g + 4 * hh);

    // ---- fragment ds_reads -> registers ----
    const int R1 = 32 * (1 - t) + ql;
    const int R2 = R1 + 32;
    bf16x8 a1[4], a2[4], ak[4];
#pragma unroll
    for (int c = 0; c < 4; ++c) {
      a1[c] = *(const bf16x8*)(RK + R1 * 64 + (((2 * c + hh) ^ (R1 & 7)) << 3));
      a2[c] = *(const bf16x8*)(RK + R2 * 64 + (((2 * c + hh) ^ (R2 & 7)) << 3));
      ak[c] = *(const bf16x8*)(KT + ql * 64 + (((2 * c + hh) ^ (ql & 7)) << 3));
    }
    bf16x8 vv0[2], vv1[2];
#pragma unroll
    for (int kh = 0; kh < 2; ++kh) {
      vv0[kh] = *(const bf16x8*)(VT + ql * 32 + (((2 * kh + hh) ^ (ql & 3)) << 3));
      vv1[kh] = *(const bf16x8*)(VT + (32 + ql) * 32 + (((2 * kh + hh) ^ (ql & 3)) << 3));
    }
    asm volatile("s_waitcnt lgkmcnt(0)");
    __builtin_amdgcn_s_barrier();        // tiles free to overwrite

    if (j0 + 32 < TLEN) STAGE(j0 + 32);  // async, hidden under compute below

    const bool t0w1 = (j0 <= q0);
    const bool t1w1 = (j0 < q0);

    // BD tile 1 -> W rows [0,32)
    f32x16 facc;
#pragma unroll
    for (int i = 0; i < 16; ++i) facc[i] = 0.f;
    __builtin_amdgcn_s_setprio(1);
#pragma unroll
    for (int c = 0; c < 4; ++c)
      facc = __builtin_amdgcn_mfma_f32_32x32x16_bf16(a1[c], t0w1 ? Qf[c] : Qs[c], facc, 0, 0, 0);
    __builtin_amdgcn_s_setprio(0);
#pragma unroll
    for (int r = 0; r < 16; ++r)
      Wp[(r & 3) + 8 * (r >> 2) + 4 * hh][ql] = facc[r];

    // BD tile 2 -> W rows [32,64)
#pragma unroll
    for (int i = 0; i < 16; ++i) facc[i] = 0.f;
    __builtin_amdgcn_s_setprio(1);
#pragma unroll
    for (int c = 0; c < 4; ++c)
      facc = __builtin_amdgcn_mfma_f32_32x32x16_bf16(a2[c], t1w1 ? Qf[c] : Qs[c], facc, 0, 0, 0);
    __builtin_amdgcn_s_setprio(0);
#pragma unroll
    for (int r = 0; r < 16; ++r)
      Wp[32 + (r & 3) + 8 * (r >> 2) + 4 * hh][ql] = facc[r];

    // AC tile (S^T)
    f32x16 cacc;
#pragma unroll
    for (int i = 0; i < 16; ++i) cacc[i] = 0.f;
    __builtin_amdgcn_s_setprio(1);
#pragma unroll
    for (int c = 0; c < 4; ++c)
      cacc = __builtin_amdgcn_mfma_f32_32x32x16_bf16(ak[c], Qf[c], cacc, 0, 0, 0);
    __builtin_amdgcn_s_setprio(0);

    float p[16];
#pragma unroll
    for (int r = 0; r < 16; ++r) {
      int jrow = (r & 3) + 8 * (r >> 2) + 4 * hh;
      float bd = Wp[jrow - ql + 31][ql];
      float sc = (cacc[r] + bd) * 0.125f;
      float mv = (&mf4[r >> 2].x)[r & 3];
      float pv = mv * __expf(sc);
      p[r] = pv;
      l_acc += pv;
    }

    unsigned int u[8];
#pragma unroll
    for (int i = 0; i < 8; ++i) u[i] = pk2(p[2 * i], p[2 * i + 1]);

    // coalesced transposed staging: S[bh][(j0+jrow)/2][qg]
#pragma unroll
    for (int i = 0; i < 8; ++i) {
      int r = 2 * i;
      int jrow = (r & 3) + 8 * (r >> 2) + 4 * hh;   // even
      Sb[(size_t)((j0 + jrow) >> 1) * TLEN + qg] = u[i];
    }

#pragma unroll
    for (int kh = 0; kh < 2; ++kh) {
      unsigned int t0 = (unsigned int)__shfl_xor((int)u[4 * kh + 0], 32);
      unsigned int t1 = (unsigned int)__shfl_xor((int)u[4 * kh + 1], 32);
      unsigned int t2 = (unsigned int)__shfl_xor((int)u[4 * kh + 2], 32);
      unsigned int t3 = (unsigned int)__shfl_xor((int)u[4 * kh + 3], 32);
      unsigned int fr[4];
      fr[0] = hh ? t2 : u[4 * kh + 0];
      fr[1] = hh ? t3 : u[4 * kh + 1];
      fr[2] = hh ? u[4 * kh + 2] : t0;
      fr[3] = hh ? u[4 * kh + 3] : t1;
      bf16x8 pa = *reinterpret_cast<bf16x8*>(fr);
      __builtin_amdgcn_s_setprio(1);
      pacc0 = __builtin_amdgcn_mfma_f32_32x32x16_bf16(pa, kh ? vv0[1] : vv0[0], pacc0, 0, 0, 0);
      pacc1 = __builtin_amdgcn_mfma_f32_32x32x16_bf16(pa, kh ? vv1[1] : vv1[0], pacc1, 0, 0, 0);
      __builtin_amdgcn_s_setprio(0);
    }

    if (j0 + 32 < TLEN) {
      // wait the 10 staging loads (oldest); S stores may stay in flight
      asm volatile("s_waitcnt vmcnt(8)");
      __builtin_amdgcn_s_barrier();      // next chunk's tiles visible
    }
  }

  // ---- wave-local epilogue ----
  float lt = l_acc + __shfl_xor(l_acc, 32);
  if (lane < 32) linv_g[(size_t)bh * TLEN + qg] = 1.0f / lt;
  float inv = 1.0f / lt;
#pragma unroll
  for (int r = 0; r < 16; ++r) {
    int qrow = (r & 3) + 8 * (r >> 2) + 4 * hh;
    float iv = __shfl(inv, qrow);
    size_t aoff = ((size_t)(q0 + qrow) * NB + b) * DMODEL + h * NDH;
    av_bf[aoff + ql] = f2bf(pacc0[r] * iv);
    av_bf[aoff + 32 + ql] = f2bf(pacc1[r] * iv);
  }
}

// ---------------------------------------------------------------------------
// Transpose-rescale: S[bh][jp][q] (bf16 j-pairs) -> prob[bh][q][j] f32 * 1/l.
// ---------------------------------------------------------------------------

__global__ __launch_bounds__(256) void rescale_t(const unsigned int* __restrict__ S,
                                                 const float* __restrict__ linv_g,
                                                 float* __restrict__ prob) {
  __shared__ unsigned int lds[64][65];
  __shared__ float liv[64];
  const int qt = blockIdx.x;   // 32 tiles of 64 q
  const int jt = blockIdx.y;   // 16 tiles of 64 jp (=128 j)
  const int bh = blockIdx.z;
  const int t = threadIdx.x;

  const unsigned int* Sb = S + ((size_t)bh * (TLEN / 2) + jt * 64) * TLEN + qt * 64;
  {
    int row = t >> 2, c0 = (t & 3) * 16;
#pragma unroll
    for (int k = 0; k < 4; ++k) {
      uint4 v = *reinterpret_cast<const uint4*>(Sb + (size_t)row * TLEN + c0 + k * 4);
      lds[row][c0 + k * 4 + 0] = v.x;
      lds[row][c0 + k * 4 + 1] = v.y;
      lds[row][c0 + k * 4 + 2] = v.z;
      lds[row][c0 + k * 4 + 3] = v.w;
    }
  }
  if (t < 64) liv[t] = linv_g[(size_t)bh * TLEN + qt * 64 + t];
  __syncthreads();

  float* P = prob + ((size_t)bh * TLEN + qt * 64) * TLEN + jt * 128;
#pragma unroll
  for (int k = 0; k < 8; ++k) {
    int idx = k * 256 + t;             // 2048 float4 = 64 rows x 32
    int row = idx >> 5, c4 = idx & 31;
    unsigned int u0 = lds[c4 * 2][row];
    unsigned int u1 = lds[c4 * 2 + 1][row];
    float iv = liv[row];
    float4 o;
    o.x = bf2f((ushortT)(u0 & 0xffff)) * iv;
    o.y = bf2f((ushortT)(u0 >> 16)) * iv;
    o.z = bf2f((ushortT)(u1 & 0xffff)) * iv;
    o.w = bf2f((ushortT)(u1 >> 16)) * iv;
    *reinterpret_cast<float4*>(P + (size_t)row * TLEN + c4 * 4) = o;
  }
}

// ---------------------------------------------------------------------------
// FALLBACK attention (unchanged): fused rescale, staging inside prob.
// Used only if d_ws is too small for the S buffer.
// ---------------------------------------------------------------------------

__global__ __launch_bounds__(256) void attn_fused(
    const ushortT* __restrict__ qb, const ushortT* __restrict__ kb,
    const ushortT* __restrict__ vtb, const ushortT* __restrict__ rkE,
    const float* __restrict__ mfl, float* __restrict__ prob,
    ushortT* __restrict__ av_bf) {
  __shared__ float W[4][64][32];
  __shared__ float sl[4][32];
  __shared__ float linv[64];

  const int bh = blockIdx.y;
  const int b = bh >> 4, h = bh & 15;
  const int wv = threadIdx.x >> 6;
  const int lane = threadIdx.x & 63;
  const int ql = lane & 31;
  const int hh = lane >> 5;
  const int qtile = wv & 1;
  const int jh = wv >> 1;
  const int q0 = blockIdx.x * 64 + qtile * 32;
  const int qg = q0 + ql;

  const ushortT* Qbh = qb + (size_t)bh * TLEN * NDH;
  const ushortT* Kbh = kb + (size_t)bh * TLEN * NDH;
  const ushortT* Vbh = vtb + (size_t)bh * NDH * TLEN;
  const ushortT* Rh  = rkE + (size_t)h * 4096 * NDH;
  const float* mflb  = mfl + (size_t)b * TLEN;
  float (*Wp)[32] = W[wv];

  bf16x8 Qf[4], Qs[4];
  {
    int r2 = min(qg + 1, TLEN - 1);
#pragma unroll
    for (int c = 0; c < 4; ++c) {
      Qf[c] = *(const bf16x8*)(Qbh + (size_t)qg * NDH + c * 16 + hh * 8);
      Qs[c] = *(const bf16x8*)(Qbh + (size_t)r2 * NDH + c * 16 + hh * 8);
    }
  }

  f32x16 pacc0, pacc1;
#pragma unroll
  for (int i = 0; i < 16; ++i) { pacc0[i] = 0.f; pacc1[i] = 0.f; }
  float l_acc = 0.f;

  ushortT* pbrow = (ushortT*)prob + ((size_t)bh * TLEN + qg) * 4096 + 2048;

  const int jbeg = jh * (TLEN / 2);
  const int jend = jbeg + (TLEN / 2);
  for (int j0 = jbeg; j0 < jend; j0 += 32) {
    const int base_t = 2016 + j0 - q0;
    const bool t0w1 = (j0 <= q0);
    const bool t1w1 = (j0 < q0);

    const ushortT* s0 = Rh + (size_t)(base_t + ql) * NDH + hh * 8;
    const ushortT* s1 = Rh + (size_t)(base_t + 32 + ql) * NDH + hh * 8;
    const ushortT* sk = Kbh + (size_t)(j0 + ql) * NDH + hh * 8;
    const ushortT* vrow0 = Vbh + (size_t)ql * TLEN + j0 + 8 * hh;
    const ushortT* vrow1 = Vbh + (size_t)(32 + ql) * TLEN + j0 + 8 * hh;
    bf16x8 rk0[4], rk1[4], kk[4];
#pragma unroll
    for (int c = 0; c < 4; ++c) {
      rk0[c] = *(const bf16x8*)(s0 + c * 16);
      rk1[c] = *(const bf16x8*)(s1 + c * 16);
      kk[c]  = *(const bf16x8*)(sk + c * 16);
    }
    bf16x8 v00 = *(const bf16x8*)(vrow0);
    bf16x8 v01 = *(const bf16x8*)(vrow0 + 16);
    bf16x8 v10 = *(const bf16x8*)(vrow1);
    bf16x8 v11 = *(const bf16x8*)(vrow1 + 16);
    float4 mf4[4];
#pragma unroll
    for (int g = 0; g < 4; ++g)
      mf4[g] = *(const float4*)(mflb + j0 + 8 * g + 4 * hh);

    f32x16 facc;
#pragma unroll
    for (int i = 0; i < 16; ++i) facc[i] = 0.f;
    __builtin_amdgcn_s_setprio(1);
#pragma unroll
    for (int c = 0; c < 4; ++c)
      facc = __builtin_amdgcn_mfma_f32_32x32x16_bf16(rk0[c], t0w1 ? Qf[c] : Qs[c], facc, 0, 0, 0);
    __builtin_amdgcn_s_setprio(0);
#pragma unroll
    for (int r = 0; r < 16; ++r)
      Wp[(r & 3) + 8 * (r >> 2) + 4 * hh][ql] = facc[r];

#pragma unroll
    for (int i = 0; i < 16; ++i) facc[i] = 0.f;
    __builtin_amdgcn_s_setprio(1);
#pragma unroll
    for (int c = 0; c < 4; ++c)
      facc = __builtin_amdgcn_mfma_f32_32x32x16_bf16(rk1[c], t1w1 ? Qf[c] : Qs[c], facc, 0, 0, 0);
    __builtin_amdgcn_s_setprio(0);
#pragma unroll
    for (int r = 0; r < 16; ++r)
      Wp[32 + (r & 3) + 8 * (r >> 2) + 4 * hh][ql] = facc[r];

    f32x16 cacc;
#pragma unroll
    for (int i = 0; i < 16; ++i) cacc[i] = 0.f;
    __builtin_amdgcn_s_setprio(1);
#pragma unroll
    for (int c = 0; c < 4; ++c)
      cacc = __builtin_amdgcn_mfma_f32_32x32x16_bf16(kk[c], Qf[c], cacc, 0, 0, 0);
    __builtin_amdgcn_s_setprio(0);

    float p[16];
#pragma unroll
    for (int r = 0; r < 16; ++r) {
      int jrow = (r & 3) + 8 * (r >> 2) + 4 * hh;
      float bd = Wp[jrow - ql + 31][ql];
      float sc = (cacc[r] + bd) * 0.125f;
      float mv = (&mf4[r >> 2].x)[r & 3];
      float pv = mv * __expf(sc);
      p[r] = pv;
      l_acc += pv;
    }

#pragma unroll
    for (int g = 0; g < 4; ++g) {
      uint2 st;
      st.x = pk2(p[4 * g + 0], p[4 * g + 1]);
      st.y = pk2(p[4 * g + 2], p[4 * g + 3]);
      *reinterpret_cast<uint2*>(pbrow + j0 + 8 * g + 4 * hh) = st;
    }

#pragma unroll
    for (int kh = 0; kh < 2; ++kh) {
      unsigned int u0 = pk2(p[8 * kh + 0], p[8 * kh + 1]);
      unsigned int u1 = pk2(p[8 * kh + 2], p[8 * kh + 3]);
      unsigned int u2 = pk2(p[8 * kh + 4], p[8 * kh + 5]);
      unsigned int u3 = pk2(p[8 * kh + 6], p[8 * kh + 7]);
      unsigned int t0 = (unsigned int)__shfl_xor((int)u0, 32);
      unsigned int t1 = (unsigned int)__shfl_xor((int)u1, 32);
      unsigned int t2 = (unsigned int)__shfl_xor((int)u2, 32);
      unsigned int t3 = (unsigned int)__shfl_xor((int)u3, 32);
      unsigned int fr[4];
      fr[0] = hh ? t2 : u0;
      fr[1] = hh ? t3 : u1;
      fr[2] = hh ? u2 : t0;
      fr[3] = hh ? u3 : t1;
      bf16x8 pa = *reinterpret_cast<bf16x8*>(fr);
      __builtin_amdgcn_s_setprio(1);
      pacc0 = __builtin_amdgcn_mfma_f32_32x32x16_bf16(pa, kh ? v01 : v00, pacc0, 0, 0, 0);
      pacc1 = __builtin_amdgcn_mfma_f32_32x32x16_bf16(pa, kh ? v11 : v10, pacc1, 0, 0, 0);
      __builtin_amdgcn_s_setprio(0);
    }
  }

#pragma unroll
  for (int r = 0; r < 16; ++r) {
    int qrow = (r & 3) + 8 * (r >> 2) + 4 * hh;
    Wp[qrow][ql] = pacc0[r];
    Wp[32 + qrow][ql] = pacc1[r];
  }
  float lh = l_acc + __shfl_xor(l_acc, 32);
  if (lane < 32) sl[wv][ql] = lh;
  __syncthreads();

  if (wv < 2) {
    if (lane < 32) {
      float lt = sl[wv][ql] + sl[wv + 2][ql];
      linv[wv * 32 + ql] = 1.0f / lt;
    }
#pragma unroll
    for (int r = 0; r < 16; ++r) {
      int qrow = (r & 3) + 8 * (r >> 2) + 4 * hh;
      float lt = sl[wv][qrow] + sl[wv + 2][qrow];
      float iv = 1.0f / lt;
      float s0v = W[wv][qrow][ql] + W[wv + 2][qrow][ql];
      float s1v = W[wv][32 + qrow][ql] + W[wv + 2][32 + qrow][ql];
      size_t aoff = ((size_t)(q0 + qrow) * NB + b) * DMODEL + h * NDH;
      av_bf[aoff + ql] = f2bf(s0v * iv);
      av_bf[aoff + 32 + ql] = f2bf(s1v * iv);
    }
  }
  __syncthreads();

  const ushortT* probus = (const ushortT*)prob;
  const int lr = lane >> 4;
  const int cg = lane & 15;
  for (int s = 0; s < 8; ++s) {
    const int rloc = qtile * 32 + s * 4 + lr;
    const int rowg = blockIdx.x * 64 + rloc;
    const size_t ub = ((size_t)bh * TLEN + rowg) * 4096 + 2048 + jh * 1024 + cg * 8;
    const size_t fb = ((size_t)bh * TLEN + rowg) * 2048 + jh * 1024 + cg * 8;
    uint4 a[8];
#pragma unroll
    for (int k = 0; k < 8; ++k)
      a[k] = *reinterpret_cast<const uint4*>(probus + ub + k * 128);
    const float iv = linv[rloc];
    __syncthreads();
#pragma unroll
    for (int k = 0; k < 8; ++k) {
      float4 o0, o1;
      o0.x = bf2f((ushortT)(a[k].x & 0xffff)) * iv;
      o0.y = bf2f((ushortT)(a[k].x >> 16)) * iv;
      o0.z = bf2f((ushortT)(a[k].y & 0xffff)) * iv;
      o0.w = bf2f((ushortT)(a[k].y >> 16)) * iv;
      o1.x = bf2f((ushortT)(a[k].z & 0xffff)) * iv;
      o1.y = bf2f((ushortT)(a[k].z >> 16)) * iv;
      o1.z = bf2f((ushortT)(a[k].w & 0xffff)) * iv;
      o1.w = bf2f((ushortT)(a[k].w >> 16)) * iv;
      *reinterpret_cast<float4*>(prob + fb + k * 128) = o0;
      *reinterpret_cast<float4*>(prob + fb + k * 128 + 4) = o1;
    }
  }
}

// ---------------------------------------------------------------------------

extern "C" void kernel_launch(void* const* d_in, const int* in_sizes, int n_in,
                              void* d_out, int out_size, void* d_ws, size_t ws_size,
                              hipStream_t stream) {
  const float* w      = (const float*)d_in[0];   // (T,B,D)
  const float* r      = (const float*)d_in[1];   // (T,D)
  const float* w_qkv  = (const float*)d_in[2];   // (3072,1024)
  const float* w_r    = (const float*)d_in[3];   // (1024,1024)
  const float* w_o    = (const float*)d_in[4];   // (1024,1024)
  const float* bias   = (const float*)d_in[5];   // (16,64)
  const int* mask     = (const int*)d_in[6];     // (T,B) int32

  float* out  = (float*)d_out;
  float* prob = out + (size_t)TLEN * NB * DMODEL;

  const size_t SZ = (size_t)NB * NH * TLEN * NDH;        // 4194304
  ushortT* w_bf    = (ushortT*)d_ws;
  ushortT* wqkv_bf = w_bf + (size_t)4096 * 1024;
  ushortT* r_bf    = wqkv_bf + (size_t)3072 * 1024;
  ushortT* wr_bf   = r_bf + (size_t)2048 * 1024;
  ushortT* wo_bf   = wr_bf + (size_t)1024 * 1024;
  ushortT* q_bf    = wo_bf + (size_t)1024 * 1024;
  ushortT* k_bf    = q_bf + SZ;
  ushortT* vt_bf   = k_bf + SZ;
  ushortT* rkE_bf  = vt_bf + SZ;                         // 16*4096*64
  ushortT* av_bf   = rkE_bf + (size_t)NH * 4096 * NDH;
  float* mfl       = (float*)(av_bf + SZ);
  float* linv_g    = mfl + (size_t)NB * TLEN;
  unsigned int* S  = (unsigned int*)(linv_g + (size_t)NB * NH * TLEN);
  const size_t need = (size_t)((char*)(S + (size_t)NB * NH * (TLEN / 2) * TLEN) -
                               (char*)d_ws);
  const bool fast = ws_size >= need;

  // fused prologue: 2883584 float4 converts + 768 tail threads
  cvt_all<<<dim3((2883584 + 768 + 255) / 256), 256, 0, stream>>>(
      w, w_qkv, r, w_r, w_o, w_bf, wqkv_bf, r_bf, wr_bf, wo_bf, mask, mfl, rkE_bf);

  EpiQKV e1{q_bf, k_bf, vt_bf, bias};
  gemm_bf16<EpiQKV><<<dim3(3072 / 128, 4096 / 128), 256, 0, stream>>>(w_bf, wqkv_bf, DMODEL, e1);
  EpiRK e2{rkE_bf};
  gemm_bf16<EpiRK><<<dim3(1024 / 128, 2048 / 128), 256, 0, stream>>>(r_bf, wr_bf, DMODEL, e2);

  if (fast) {
    attn_fast<<<dim3(32, 32), 128, 0, stream>>>(q_bf, k_bf, vt_bf, rkE_bf,
                                                mfl, S, linv_g, av_bf);
    rescale_t<<<dim3(32, 16, 32), 256, 0, stream>>>(S, linv_g, prob);
  } else {
    attn_fused<<<dim3(32, 32), 256, 0, stream>>>(q_bf, k_bf, vt_bf, rkE_bf,
                                                 mfl, prob, av_bf);
  }

  EpiOut e5{out};
  gemm_bf16<EpiOut><<<dim3(1024 / 128, 4096 / 128), 256, 0, stream>>>(av_bf, wo_bf, DMODEL, e5);
}

// Round 12
// 461.660 us; speedup vs baseline: 1.0006x; 1.0006x over previous
//
#include <hip/hip_runtime.h>
#include <hip/hip_bf16.h>
#include <cstdint>
#include <cstddef>

#define TLEN 2048
#define NB 2
#define DMODEL 1024
#define NH 16
#define NDH 64

typedef unsigned short ushortT;
typedef short bf16x8 __attribute__((ext_vector_type(8)));
typedef float f32x16 __attribute__((ext_vector_type(16)));

__device__ __forceinline__ ushortT f2bf(float f) {
  union { float f; unsigned int u; } x{f};
  unsigned int r = x.u + 0x7fff + ((x.u >> 16) & 1);   // RNE
  return (ushortT)(r >> 16);
}
__device__ __forceinline__ unsigned int pk2(float lo, float hi) {
  return ((unsigned int)f2bf(hi) << 16) | (unsigned int)f2bf(lo);
}
__device__ __forceinline__ float bf2f(ushortT u) {
  union { unsigned int u; float f; } x;
  x.u = ((unsigned int)u) << 16;
  return x.f;
}

__device__ __forceinline__ void gld_lds16(const void* g, void* l) {
  __builtin_amdgcn_global_load_lds(
      (const __attribute__((address_space(1))) unsigned int*)g,
      (__attribute__((address_space(3))) unsigned int*)l, 16, 0, 0);
}

// ---------------------------------------------------------------------------
// fused prologue: all f32->bf16 converts + mask floats + rk_ext zero row
// ---------------------------------------------------------------------------

__global__ __launch_bounds__(256) void cvt_all(
    const float* __restrict__ w, const float* __restrict__ wqkv,
    const float* __restrict__ r, const float* __restrict__ wr,
    const float* __restrict__ wo, ushortT* __restrict__ w_bf,
    ushortT* __restrict__ wqkv_bf, ushortT* __restrict__ r_bf,
    ushortT* __restrict__ wr_bf, ushortT* __restrict__ wo_bf,
    const int* __restrict__ mask, float* __restrict__ mfl,
    ushortT* __restrict__ rkE) {
  const size_t N0 = 1048576, N1 = N0 + 786432, N2 = N1 + 524288,
               N3 = N2 + 262144, N4 = N3 + 262144;
  size_t i = (size_t)blockIdx.x * 256 + threadIdx.x;
  const float* src; ushortT* dst; size_t off;
  if (i < N0)      { src = w;    dst = w_bf;    off = i; }
  else if (i < N1) { src = wqkv; dst = wqkv_bf; off = i - N0; }
  else if (i < N2) { src = r;    dst = r_bf;    off = i - N1; }
  else if (i < N3) { src = wr;   dst = wr_bf;   off = i - N2; }
  else if (i < N4) { src = wo;   dst = wo_bf;   off = i - N3; }
  else {
    size_t k = i - N4;
    if (k < 512) {                       // mask floats: 4 j per thread
      int j = (int)k * 4;
#pragma unroll
      for (int s = 0; s < 4; ++s) {
        mfl[j + s]        = mask[(size_t)(j + s) * NB]     ? 0.f : 1.f;
        mfl[TLEN + j + s] = mask[(size_t)(j + s) * NB + 1] ? 0.f : 1.f;
      }
    } else if (k < 512 + 256) {          // rk_ext zero row per head
      int ii = (int)k - 512; int h = ii >> 4, c = ii & 15;
      ushort4 z; z.x = 0; z.y = 0; z.z = 0; z.w = 0;
      *reinterpret_cast<ushort4*>(rkE + ((size_t)h * 4096 + 2048) * NDH + c * 4) = z;
    }
    return;
  }
  float4 v = reinterpret_cast<const float4*>(src)[off];
  ushort4 o;
  o.x = f2bf(v.x); o.y = f2bf(v.y); o.z = f2bf(v.z); o.w = f2bf(v.w);
  reinterpret_cast<ushort4*>(dst)[off] = o;
}

// ---------------------------------------------------------------------------
// bf16 MFMA GEMM, K-loop pipelined (kept from R11): fragments to regs ->
// lgkmcnt -> barrier -> stage next K-tile (in flight over MFMA) -> MFMA ->
// vmcnt(0) -> barrier
// ---------------------------------------------------------------------------

template <typename Epi>
__global__ __launch_bounds__(256) void gemm_bf16(const ushortT* __restrict__ A,
                                                 const ushortT* __restrict__ B,
                                                 int K, Epi epi) {
  __shared__ ushortT Al[128 * 64];
  __shared__ ushortT Bl[128 * 64];
  const int tid = threadIdx.x;
  const int lane = tid & 63;
  const int wv = tid >> 6;
  const int wm = wv >> 1, wn = wv & 1;
  const int m0 = blockIdx.y * 128;
  const int n0 = blockIdx.x * 128;
  const int r32 = lane & 31;
  const int hh = lane >> 5;

  auto STAGE = [&](int k0) {
#pragma unroll
    for (int it = 0; it < 4; ++it) {
      int idx = it * 256 + tid;          // 1024 chunks of 16B
      int r = idx >> 3, c = idx & 7;
      int gcol = k0 + ((c ^ (r & 7)) << 3);
      gld_lds16(A + (size_t)(m0 + r) * K + gcol, Al + idx * 8);
      gld_lds16(B + (size_t)(n0 + r) * K + gcol, Bl + idx * 8);
    }
  };

  f32x16 acc[2][2];
#pragma unroll
  for (int i = 0; i < 2; ++i)
#pragma unroll
    for (int j = 0; j < 2; ++j)
#pragma unroll
      for (int e = 0; e < 16; ++e) acc[i][j][e] = 0.f;

  STAGE(0);
  asm volatile("s_waitcnt vmcnt(0)");
  __builtin_amdgcn_s_barrier();

  for (int k0 = 0; k0 < K; k0 += 64) {
    bf16x8 af[4][2], bfr[4][2];
#pragma unroll
    for (int kc = 0; kc < 4; ++kc) {
      int lc = kc * 2 + hh;              // logical 16B chunk in row
#pragma unroll
      for (int f = 0; f < 2; ++f) {
        int ar = wm * 64 + f * 32 + r32;
        af[kc][f] = *(const bf16x8*)(Al + ar * 64 + ((lc ^ (ar & 7)) << 3));
        int br = wn * 64 + f * 32 + r32;
        bfr[kc][f] = *(const bf16x8*)(Bl + br * 64 + ((lc ^ (br & 7)) << 3));
      }
    }
    asm volatile("s_waitcnt lgkmcnt(0)");
    __builtin_amdgcn_s_barrier();        // LDS free to overwrite

    if (k0 + 64 < K) STAGE(k0 + 64);     // in flight across the MFMAs

    __builtin_amdgcn_s_setprio(1);
#pragma unroll
    for (int kc = 0; kc < 4; ++kc)
#pragma unroll
      for (int i = 0; i < 2; ++i)
#pragma unroll
        for (int j = 0; j < 2; ++j)
          acc[i][j] = __builtin_amdgcn_mfma_f32_32x32x16_bf16(af[kc][i], bfr[kc][j],
                                                              acc[i][j], 0, 0, 0);
    __builtin_amdgcn_s_setprio(0);

    if (k0 + 64 < K) {
      asm volatile("s_waitcnt vmcnt(0)");
      __builtin_amdgcn_s_barrier();      // next tile visible
    }
  }

#pragma unroll
  for (int i = 0; i < 2; ++i)
#pragma unroll
    for (int j = 0; j < 2; ++j)
#pragma unroll
      for (int rg = 0; rg < 16; ++rg) {
        int m = m0 + wm * 64 + i * 32 + (rg & 3) + 8 * (rg >> 2) + 4 * hh;
        int n = n0 + wn * 64 + j * 32 + r32;
        epi.store(m, n, acc[i][j][rg]);
      }
}

struct EpiQKV {
  ushortT* qb; ushortT* kb; ushortT* vtb; const float* bias;
  __device__ void store(int m, int n, float val) const {
    int t = m >> 1, b = m & 1;
    int which = n >> 10;
    int h = (n >> 6) & (NH - 1);
    int dh = n & (NDH - 1);
    int bh = b * NH + h;
    if (which == 0)
      qb[((size_t)bh * TLEN + t) * NDH + dh] = f2bf(val + bias[(h << 6) | dh]);
    else if (which == 1)
      kb[((size_t)bh * TLEN + t) * NDH + dh] = f2bf(val);
    else
      vtb[((size_t)bh * NDH + dh) * TLEN + t] = f2bf(val);
  }
};

struct EpiRK {   // rk_ext: row m = rk[m] (m<=2047); row 2048 = 0 (cvt_all);
                 // row m = rk[m-2049] (m>=2049)
  ushortT* rkE;
  __device__ void store(int m, int n, float val) const {
    int h = n >> 6, dh = n & 63;
    ushortT v = f2bf(val);
    rkE[((size_t)h * 4096 + m) * NDH + dh] = v;
    if (m <= 2046)
      rkE[((size_t)h * 4096 + m + 2049) * NDH + dh] = v;
  }
};

struct EpiOut {
  float* out;
  __device__ void store(int m, int n, float val) const {
    out[(size_t)m * DMODEL + n] = val;
  }
};

// ---------------------------------------------------------------------------
// FAST attention (exact R10 form — XCD swizzle reverted, twice-failed).
// Grid (32,32): blockIdx.y = bh, blockIdx.x = 64 q rows; 2 waves/block.
// LDS-staged + single-buffer software pipeline with counted vmcnt(8).
// ---------------------------------------------------------------------------

__global__ __launch_bounds__(128) void attn_fast(
    const ushortT* __restrict__ qb, const ushortT* __restrict__ kb,
    const ushortT* __restrict__ vtb, const ushortT* __restrict__ rkE,
    const float* __restrict__ mfl, unsigned int* __restrict__ S,
    float* __restrict__ linv_g, ushortT* __restrict__ av_bf) {
  __shared__ float W[2][64][32];
  __shared__ ushortT KT[2048];   // [32 j][8 x 16B chunks], chunk c at c^(row&7)
  __shared__ ushortT VT[2048];   // [64 d][4 x 16B chunks], chunk c at c^(d&3)
  __shared__ ushortT RK[6144];   // [96 rows][8 chunks],    chunk c at c^(row&7)

  const int bh = blockIdx.y;
  const int b = bh >> 4, h = bh & 15;
  const int t = threadIdx.x >> 6;        // q-tile wave
  const int lane = threadIdx.x & 63;
  const int ql = lane & 31;
  const int hh = lane >> 5;
  const int Q0 = blockIdx.x * 64;
  const int q0 = Q0 + 32 * t;
  const int qg = q0 + ql;

  const ushortT* Qbh = qb + (size_t)bh * TLEN * NDH;
  const ushortT* Kbh = kb + (size_t)bh * TLEN * NDH;
  const ushortT* Vbh = vtb + (size_t)bh * NDH * TLEN;
  const ushortT* Rh  = rkE + (size_t)h * 4096 * NDH;
  const float* mflb  = mfl + (size_t)b * TLEN;
  unsigned int* Sb   = S + (size_t)bh * (TLEN / 2) * TLEN;
  float (*Wp)[32] = W[t];

  auto STAGE = [&](int j0) {
    const int U = 1984 + j0 - Q0;        // in [0, 4000]; U+96 <= 4096
#pragma unroll
    for (int i = 0; i < 6; ++i) {        // RK: 6 insts/wave
      int ci = (t * 6 + i) * 64 + lane;
      int row = ci >> 3, c = ci & 7;
      gld_lds16(Rh + (size_t)(U + row) * NDH + ((c ^ (row & 7)) << 3), RK + ci * 8);
    }
#pragma unroll
    for (int i = 0; i < 2; ++i) {        // KT + VT: 2+2 insts/wave
      int ci = (t * 2 + i) * 64 + lane;
      int row = ci >> 3, c = ci & 7;
      gld_lds16(Kbh + (size_t)(j0 + row) * NDH + ((c ^ (row & 7)) << 3), KT + ci * 8);
      int d = ci >> 2, c2 = ci & 3;
      gld_lds16(Vbh + (size_t)d * TLEN + j0 + ((c2 ^ (d & 3)) << 3), VT + ci * 8);
    }
  };

  bf16x8 Qf[4], Qs[4];
  {
    int r2 = min(qg + 1, TLEN - 1);
#pragma unroll
    for (int c = 0; c < 4; ++c) {
      Qf[c] = *(const bf16x8*)(Qbh + (size_t)qg * NDH + c * 16 + hh * 8);
      Qs[c] = *(const bf16x8*)(Qbh + (size_t)r2 * NDH + c * 16 + hh * 8);
    }
  }

  f32x16 pacc0, pacc1;
#pragma unroll
  for (int i = 0; i < 16; ++i) { pacc0[i] = 0.f; pacc1[i] = 0.f; }
  float l_acc = 0.f;

  // prologue: stage chunk 0, full drain
  STAGE(0);
  asm volatile("s_waitcnt vmcnt(0)");
  __builtin_amdgcn_s_barrier();

  for (int j0 = 0; j0 < TLEN; j0 += 32) {
    // current-chunk mask loads (oldest VMEM after stores -> cheap wait at exp)
    float4 mf4[4];
#pragma unroll
    for (int g = 0; g < 4; ++g)
      mf4[g] = *(const float4*)(mflb + j0 + 8 * g + 4 * hh);

    // ---- fragment ds_reads -> registers ----
    const int R1 = 32 * (1 - t) + ql;
    const int R2 = R1 + 32;
    bf16x8 a1[4], a2[4], ak[4];
#pragma unroll
    for (int c = 0; c < 4; ++c) {
      a1[c] = *(const bf16x8*)(RK + R1 * 64 + (((2 * c + hh) ^ (R1 & 7)) << 3));
      a2[c] = *(const bf16x8*)(RK + R2 * 64 + (((2 * c + hh) ^ (R2 & 7)) << 3));
      ak[c] = *(const bf16x8*)(KT + ql * 64 + (((2 * c + hh) ^ (ql & 7)) << 3));
    }
    bf16x8 vv0[2], vv1[2];
#pragma unroll
    for (int kh = 0; kh < 2; ++kh) {
      vv0[kh] = *(const bf16x8*)(VT + ql * 32 + (((2 * kh + hh) ^ (ql & 3)) << 3));
      vv1[kh] = *(const bf16x8*)(VT + (32 + ql) * 32 + (((2 * kh + hh) ^ (ql & 3)) << 3));
    }
    asm volatile("s_waitcnt lgkmcnt(0)");
    __builtin_amdgcn_s_barrier();        // tiles free to overwrite

    if (j0 + 32 < TLEN) STAGE(j0 + 32);  // async, hidden under compute below

    const bool t0w1 = (j0 <= q0);
    const bool t1w1 = (j0 < q0);

    // BD tile 1 -> W rows [0,32)
    f32x16 facc;
#pragma unroll
    for (int i = 0; i < 16; ++i) facc[i] = 0.f;
    __builtin_amdgcn_s_setprio(1);
#pragma unroll
    for (int c = 0; c < 4; ++c)
      facc = __builtin_amdgcn_mfma_f32_32x32x16_bf16(a1[c], t0w1 ? Qf[c] : Qs[c], facc, 0, 0, 0);
    __builtin_amdgcn_s_setprio(0);
#pragma unroll
    for (int r = 0; r < 16; ++r)
      Wp[(r & 3) + 8 * (r >> 2) + 4 * hh][ql] = facc[r];

    // BD tile 2 -> W rows [32,64)
#pragma unroll
    for (int i = 0; i < 16; ++i) facc[i] = 0.f;
    __builtin_amdgcn_s_setprio(1);
#pragma unroll
    for (int c = 0; c < 4; ++c)
      facc = __builtin_amdgcn_mfma_f32_32x32x16_bf16(a2[c], t1w1 ? Qf[c] : Qs[c], facc, 0, 0, 0);
    __builtin_amdgcn_s_setprio(0);
#pragma unroll
    for (int r = 0; r < 16; ++r)
      Wp[32 + (r & 3) + 8 * (r >> 2) + 4 * hh][ql] = facc[r];

    // AC tile (S^T)
    f32x16 cacc;
#pragma unroll
    for (int i = 0; i < 16; ++i) cacc[i] = 0.f;
    __builtin_amdgcn_s_setprio(1);
#pragma unroll
    for (int c = 0; c < 4; ++c)
      cacc = __builtin_amdgcn_mfma_f32_32x32x16_bf16(ak[c], Qf[c], cacc, 0, 0, 0);
    __builtin_amdgcn_s_setprio(0);

    float p[16];
#pragma unroll
    for (int r = 0; r < 16; ++r) {
      int jrow = (r & 3) + 8 * (r >> 2) + 4 * hh;
      float bd = Wp[jrow - ql + 31][ql];
      float sc = (cacc[r] + bd) * 0.125f;
      float mv = (&mf4[r >> 2].x)[r & 3];
      float pv = mv * __expf(sc);
      p[r] = pv;
      l_acc += pv;
    }

    unsigned int u[8];
#pragma unroll
    for (int i = 0; i < 8; ++i) u[i] = pk2(p[2 * i], p[2 * i + 1]);

    // coalesced transposed staging: S[bh][(j0+jrow)/2][qg]
#pragma unroll
    for (int i = 0; i < 8; ++i) {
      int r = 2 * i;
      int jrow = (r & 3) + 8 * (r >> 2) + 4 * hh;   // even
      Sb[(size_t)((j0 + jrow) >> 1) * TLEN + qg] = u[i];
    }

#pragma unroll
    for (int kh = 0; kh < 2; ++kh) {
      unsigned int t0 = (unsigned int)__shfl_xor((int)u[4 * kh + 0], 32);
      unsigned int t1 = (unsigned int)__shfl_xor((int)u[4 * kh + 1], 32);
      unsigned int t2 = (unsigned int)__shfl_xor((int)u[4 * kh + 2], 32);
      unsigned int t3 = (unsigned int)__shfl_xor((int)u[4 * kh + 3], 32);
      unsigned int fr[4];
      fr[0] = hh ? t2 : u[4 * kh + 0];
      fr[1] = hh ? t3 : u[4 * kh + 1];
      fr[2] = hh ? u[4 * kh + 2] : t0;
      fr[3] = hh ? u[4 * kh + 3] : t1;
      bf16x8 pa = *reinterpret_cast<bf16x8*>(fr);
      __builtin_amdgcn_s_setprio(1);
      pacc0 = __builtin_amdgcn_mfma_f32_32x32x16_bf16(pa, kh ? vv0[1] : vv0[0], pacc0, 0, 0, 0);
      pacc1 = __builtin_amdgcn_mfma_f32_32x32x16_bf16(pa, kh ? vv1[1] : vv1[0], pacc1, 0, 0, 0);
      __builtin_amdgcn_s_setprio(0);
    }

    if (j0 + 32 < TLEN) {
      // wait the 10 staging loads (oldest); S stores may stay in flight
      asm volatile("s_waitcnt vmcnt(8)");
      __builtin_amdgcn_s_barrier();      // next chunk's tiles visible
    }
  }

  // ---- wave-local epilogue ----
  float lt = l_acc + __shfl_xor(l_acc, 32);
  if (lane < 32) linv_g[(size_t)bh * TLEN + qg] = 1.0f / lt;
  float inv = 1.0f / lt;
#pragma unroll
  for (int r = 0; r < 16; ++r) {
    int qrow = (r & 3) + 8 * (r >> 2) + 4 * hh;
    float iv = __shfl(inv, qrow);
    size_t aoff = ((size_t)(q0 + qrow) * NB + b) * DMODEL + h * NDH;
    av_bf[aoff + ql] = f2bf(pacc0[r] * iv);
    av_bf[aoff + 32 + ql] = f2bf(pacc1[r] * iv);
  }
}

// ---------------------------------------------------------------------------
// Transpose-rescale: S[bh][jp][q] (bf16 j-pairs) -> prob[bh][q][j] f32 * 1/l.
// ---------------------------------------------------------------------------

__global__ __launch_bounds__(256) void rescale_t(const unsigned int* __restrict__ S,
                                                 const float* __restrict__ linv_g,
                                                 float* __restrict__ prob) {
  __shared__ unsigned int lds[64][65];
  __shared__ float liv[64];
  const int qt = blockIdx.x;   // 32 tiles of 64 q
  const int jt = blockIdx.y;   // 16 tiles of 64 jp (=128 j)
  const int bh = blockIdx.z;
  const int t = threadIdx.x;

  const unsigned int* Sb = S + ((size_t)bh * (TLEN / 2) + jt * 64) * TLEN + qt * 64;
  {
    int row = t >> 2, c0 = (t & 3) * 16;
#pragma unroll
    for (int k = 0; k < 4; ++k) {
      uint4 v = *reinterpret_cast<const uint4*>(Sb + (size_t)row * TLEN + c0 + k * 4);
      lds[row][c0 + k * 4 + 0] = v.x;
      lds[row][c0 + k * 4 + 1] = v.y;
      lds[row][c0 + k * 4 + 2] = v.z;
      lds[row][c0 + k * 4 + 3] = v.w;
    }
  }
  if (t < 64) liv[t] = linv_g[(size_t)bh * TLEN + qt * 64 + t];
  __syncthreads();

  float* P = prob + ((size_t)bh * TLEN + qt * 64) * TLEN + jt * 128;
#pragma unroll
  for (int k = 0; k < 8; ++k) {
    int idx = k * 256 + t;             // 2048 float4 = 64 rows x 32
    int row = idx >> 5, c4 = idx & 31;
    unsigned int u0 = lds[c4 * 2][row];
    unsigned int u1 = lds[c4 * 2 + 1][row];
    float iv = liv[row];
    float4 o;
    o.x = bf2f((ushortT)(u0 & 0xffff)) * iv;
    o.y = bf2f((ushortT)(u0 >> 16)) * iv;
    o.z = bf2f((ushortT)(u1 & 0xffff)) * iv;
    o.w = bf2f((ushortT)(u1 >> 16)) * iv;
    *reinterpret_cast<float4*>(P + (size_t)row * TLEN + c4 * 4) = o;
  }
}

// ---------------------------------------------------------------------------
// FALLBACK attention (unchanged): fused rescale, staging inside prob.
// Used only if d_ws is too small for the S buffer.
// ---------------------------------------------------------------------------

__global__ __launch_bounds__(256) void attn_fused(
    const ushortT* __restrict__ qb, const ushortT* __restrict__ kb,
    const ushortT* __restrict__ vtb, const ushortT* __restrict__ rkE,
    const float* __restrict__ mfl, float* __restrict__ prob,
    ushortT* __restrict__ av_bf) {
  __shared__ float W[4][64][32];
  __shared__ float sl[4][32];
  __shared__ float linv[64];

  const int bh = blockIdx.y;
  const int b = bh >> 4, h = bh & 15;
  const int wv = threadIdx.x >> 6;
  const int lane = threadIdx.x & 63;
  const int ql = lane & 31;
  const int hh = lane >> 5;
  const int qtile = wv & 1;
  const int jh = wv >> 1;
  const int q0 = blockIdx.x * 64 + qtile * 32;
  const int qg = q0 + ql;

  const ushortT* Qbh = qb + (size_t)bh * TLEN * NDH;
  const ushortT* Kbh = kb + (size_t)bh * TLEN * NDH;
  const ushortT* Vbh = vtb + (size_t)bh * NDH * TLEN;
  const ushortT* Rh  = rkE + (size_t)h * 4096 * NDH;
  const float* mflb  = mfl + (size_t)b * TLEN;
  float (*Wp)[32] = W[wv];

  bf16x8 Qf[4], Qs[4];
  {
    int r2 = min(qg + 1, TLEN - 1);
#pragma unroll
    for (int c = 0; c < 4; ++c) {
      Qf[c] = *(const bf16x8*)(Qbh + (size_t)qg * NDH + c * 16 + hh * 8);
      Qs[c] = *(const bf16x8*)(Qbh + (size_t)r2 * NDH + c * 16 + hh * 8);
    }
  }

  f32x16 pacc0, pacc1;
#pragma unroll
  for (int i = 0; i < 16; ++i) { pacc0[i] = 0.f; pacc1[i] = 0.f; }
  float l_acc = 0.f;

  ushortT* pbrow = (ushortT*)prob + ((size_t)bh * TLEN + qg) * 4096 + 2048;

  const int jbeg = jh * (TLEN / 2);
  const int jend = jbeg + (TLEN / 2);
  for (int j0 = jbeg; j0 < jend; j0 += 32) {
    const int base_t = 2016 + j0 - q0;
    const bool t0w1 = (j0 <= q0);
    const bool t1w1 = (j0 < q0);

    const ushortT* s0 = Rh + (size_t)(base_t + ql) * NDH + hh * 8;
    const ushortT* s1 = Rh + (size_t)(base_t + 32 + ql) * NDH + hh * 8;
    const ushortT* sk = Kbh + (size_t)(j0 + ql) * NDH + hh * 8;
    const ushortT* vrow0 = Vbh + (size_t)ql * TLEN + j0 + 8 * hh;
    const ushortT* vrow1 = Vbh + (size_t)(32 + ql) * TLEN + j0 + 8 * hh;
    bf16x8 rk0[4], rk1[4], kk[4];
#pragma unroll
    for (int c = 0; c < 4; ++c) {
      rk0[c] = *(const bf16x8*)(s0 + c * 16);
      rk1[c] = *(const bf16x8*)(s1 + c * 16);
      kk[c]  = *(const bf16x8*)(sk + c * 16);
    }
    bf16x8 v00 = *(const bf16x8*)(vrow0);
    bf16x8 v01 = *(const bf16x8*)(vrow0 + 16);
    bf16x8 v10 = *(const bf16x8*)(vrow1);
    bf16x8 v11 = *(const bf16x8*)(vrow1 + 16);
    float4 mf4[4];
#pragma unroll
    for (int g = 0; g < 4; ++g)
      mf4[g] = *(const float4*)(mflb + j0 + 8 * g + 4 * hh);

    f32x16 facc;
#pragma unroll
    for (int i = 0; i < 16; ++i) facc[i] = 0.f;
    __builtin_amdgcn_s_setprio(1);
#pragma unroll
    for (int c = 0; c < 4; ++c)
      facc = __builtin_amdgcn_mfma_f32_32x32x16_bf16(rk0[c], t0w1 ? Qf[c] : Qs[c], facc, 0, 0, 0);
    __builtin_amdgcn_s_setprio(0);
#pragma unroll
    for (int r = 0; r < 16; ++r)
      Wp[(r & 3) + 8 * (r >> 2) + 4 * hh][ql] = facc[r];

#pragma unroll
    for (int i = 0; i < 16; ++i) facc[i] = 0.f;
    __builtin_amdgcn_s_setprio(1);
#pragma unroll
    for (int c = 0; c < 4; ++c)
      facc = __builtin_amdgcn_mfma_f32_32x32x16_bf16(rk1[c], t1w1 ? Qf[c] : Qs[c], facc, 0, 0, 0);
    __builtin_amdgcn_s_setprio(0);
#pragma unroll
    for (int r = 0; r < 16; ++r)
      Wp[32 + (r & 3) + 8 * (r >> 2) + 4 * hh][ql] = facc[r];

    f32x16 cacc;
#pragma unroll
    for (int i = 0; i < 16; ++i) cacc[i] = 0.f;
    __builtin_amdgcn_s_setprio(1);
#pragma unroll
    for (int c = 0; c < 4; ++c)
      cacc = __builtin_amdgcn_mfma_f32_32x32x16_bf16(kk[c], Qf[c], cacc, 0, 0, 0);
    __builtin_amdgcn_s_setprio(0);

    float p[16];
#pragma unroll
    for (int r = 0; r < 16; ++r) {
      int jrow = (r & 3) + 8 * (r >> 2) + 4 * hh;
      float bd = Wp[jrow - ql + 31][ql];
      float sc = (cacc[r] + bd) * 0.125f;
      float mv = (&mf4[r >> 2].x)[r & 3];
      float pv = mv * __expf(sc);
      p[r] = pv;
      l_acc += pv;
    }

#pragma unroll
    for (int g = 0; g < 4; ++g) {
      uint2 st;
      st.x = pk2(p[4 * g + 0], p[4 * g + 1]);
      st.y = pk2(p[4 * g + 2], p[4 * g + 3]);
      *reinterpret_cast<uint2*>(pbrow + j0 + 8 * g + 4 * hh) = st;
    }

#pragma unroll
    for (int kh = 0; kh < 2; ++kh) {
      unsigned int u0 = pk2(p[8 * kh + 0], p[8 * kh + 1]);
      unsigned int u1 = pk2(p[8 * kh + 2], p[8 * kh + 3]);
      unsigned int u2 = pk2(p[8 * kh + 4], p[8 * kh + 5]);
      unsigned int u3 = pk2(p[8 * kh + 6], p[8 * kh + 7]);
      unsigned int t0 = (unsigned int)__shfl_xor((int)u0, 32);
      unsigned int t1 = (unsigned int)__shfl_xor((int)u1, 32);
      unsigned int t2 = (unsigned int)__shfl_xor((int)u2, 32);
      unsigned int t3 = (unsigned int)__shfl_xor((int)u3, 32);
      unsigned int fr[4];
      fr[0] = hh ? t2 : u0;
      fr[1] = hh ? t3 : u1;
      fr[2] = hh ? u2 : t0;
      fr[3] = hh ? u3 : t1;
      bf16x8 pa = *reinterpret_cast<bf16x8*>(fr);
      __builtin_amdgcn_s_setprio(1);
      pacc0 = __builtin_amdgcn_mfma_f32_32x32x16_bf16(pa, kh ? v01 : v00, pacc0, 0, 0, 0);
      pacc1 = __builtin_amdgcn_mfma_f32_32x32x16_bf16(pa, kh ? v11 : v10, pacc1, 0, 0, 0);
      __builtin_amdgcn_s_setprio(0);
    }
  }

#pragma unroll
  for (int r = 0; r < 16; ++r) {
    int qrow = (r & 3) + 8 * (r >> 2) + 4 * hh;
    Wp[qrow][ql] = pacc0[r];
    Wp[32 + qrow][ql] = pacc1[r];
  }
  float lh = l_acc + __shfl_xor(l_acc, 32);
  if (lane < 32) sl[wv][ql] = lh;
  __syncthreads();

  if (wv < 2) {
    if (lane < 32) {
      float lt = sl[wv][ql] + sl[wv + 2][ql];
      linv[wv * 32 + ql] = 1.0f / lt;
    }
#pragma unroll
    for (int r = 0; r < 16; ++r) {
      int qrow = (r & 3) + 8 * (r >> 2) + 4 * hh;
      float lt = sl[wv][qrow] + sl[wv + 2][qrow];
      float iv = 1.0f / lt;
      float s0v = W[wv][qrow][ql] + W[wv + 2][qrow][ql];
      float s1v = W[wv][32 + qrow][ql] + W[wv + 2][32 + qrow][ql];
      size_t aoff = ((size_t)(q0 + qrow) * NB + b) * DMODEL + h * NDH;
      av_bf[aoff + ql] = f2bf(s0v * iv);
      av_bf[aoff + 32 + ql] = f2bf(s1v * iv);
    }
  }
  __syncthreads();

  const ushortT* probus = (const ushortT*)prob;
  const int lr = lane >> 4;
  const int cg = lane & 15;
  for (int s = 0; s < 8; ++s) {
    const int rloc = qtile * 32 + s * 4 + lr;
    const int rowg = blockIdx.x * 64 + rloc;
    const size_t ub = ((size_t)bh * TLEN + rowg) * 4096 + 2048 + jh * 1024 + cg * 8;
    const size_t fb = ((size_t)bh * TLEN + rowg) * 2048 + jh * 1024 + cg * 8;
    uint4 a[8];
#pragma unroll
    for (int k = 0; k < 8; ++k)
      a[k] = *reinterpret_cast<const uint4*>(probus + ub + k * 128);
    const float iv = linv[rloc];
    __syncthreads();
#pragma unroll
    for (int k = 0; k < 8; ++k) {
      float4 o0, o1;
      o0.x = bf2f((ushortT)(a[k].x & 0xffff)) * iv;
      o0.y = bf2f((ushortT)(a[k].x >> 16)) * iv;
      o0.z = bf2f((ushortT)(a[k].y & 0xffff)) * iv;
      o0.w = bf2f((ushortT)(a[k].y >> 16)) * iv;
      o1.x = bf2f((ushortT)(a[k].z & 0xffff)) * iv;
      o1.y = bf2f((ushortT)(a[k].z >> 16)) * iv;
      o1.z = bf2f((ushortT)(a[k].w & 0xffff)) * iv;
      o1.w = bf2f((ushortT)(a[k].w >> 16)) * iv;
      *reinterpret_cast<float4*>(prob + fb + k * 128) = o0;
      *reinterpret_cast<float4*>(prob + fb + k * 128 + 4) = o1;
    }
  }
}

// ---------------------------------------------------------------------------

extern "C" void kernel_launch(void* const* d_in, const int* in_sizes, int n_in,
                              void* d_out, int out_size, void* d_ws, size_t ws_size,
                              hipStream_t stream) {
  const float* w      = (const float*)d_in[0];   // (T,B,D)
  const float* r      = (const float*)d_in[1];   // (T,D)
  const float* w_qkv  = (const float*)d_in[2];   // (3072,1024)
  const float* w_r    = (const float*)d_in[3];   // (1024,1024)
  const float* w_o    = (const float*)d_in[4];   // (1024,1024)
  const float* bias   = (const float*)d_in[5];   // (16,64)
  const int* mask     = (const int*)d_in[6];     // (T,B) int32

  float* out  = (float*)d_out;
  float* prob = out + (size_t)TLEN * NB * DMODEL;

  const size_t SZ = (size_t)NB * NH * TLEN * NDH;        // 4194304
  ushortT* w_bf    = (ushortT*)d_ws;
  ushortT* wqkv_bf = w_bf + (size_t)4096 * 1024;
  ushortT* r_bf    = wqkv_bf + (size_t)3072 * 1024;
  ushortT* wr_bf   = r_bf + (size_t)2048 * 1024;
  ushortT* wo_bf   = wr_bf + (size_t)1024 * 1024;
  ushortT* q_bf    = wo_bf + (size_t)1024 * 1024;
  ushortT* k_bf    = q_bf + SZ;
  ushortT* vt_bf   = k_bf + SZ;
  ushortT* rkE_bf  = vt_bf + SZ;                         // 16*4096*64
  ushortT* av_bf   = rkE_bf + (size_t)NH * 4096 * NDH;
  float* mfl       = (float*)(av_bf + SZ);
  float* linv_g    = mfl + (size_t)NB * TLEN;
  unsigned int* S  = (unsigned int*)(linv_g + (size_t)NB * NH * TLEN);
  const size_t need = (size_t)((char*)(S + (size_t)NB * NH * (TLEN / 2) * TLEN) -
                               (char*)d_ws);
  const bool fast = ws_size >= need;

  // fused prologue: 2883584 float4 converts + 768 tail threads
  cvt_all<<<dim3((2883584 + 768 + 255) / 256), 256, 0, stream>>>(
      w, w_qkv, r, w_r, w_o, w_bf, wqkv_bf, r_bf, wr_bf, wo_bf, mask, mfl, rkE_bf);

  EpiQKV e1{q_bf, k_bf, vt_bf, bias};
  gemm_bf16<EpiQKV><<<dim3(3072 / 128, 4096 / 128), 256, 0, stream>>>(w_bf, wqkv_bf, DMODEL, e1);
  EpiRK e2{rkE_bf};
  gemm_bf16<EpiRK><<<dim3(1024 / 128, 2048 / 128), 256, 0, stream>>>(r_bf, wr_bf, DMODEL, e2);

  if (fast) {
    attn_fast<<<dim3(32, 32), 128, 0, stream>>>(q_bf, k_bf, vt_bf, rkE_bf,
                                                mfl, S, linv_g, av_bf);
    rescale_t<<<dim3(32, 16, 32), 256, 0, stream>>>(S, linv_g, prob);
  } else {
    attn_fused<<<dim3(32, 32), 256, 0, stream>>>(q_bf, k_bf, vt_bf, rkE_bf,
                                                 mfl, prob, av_bf);
  }

  EpiOut e5{out};
  gemm_bf16<EpiOut><<<dim3(1024 / 128, 4096 / 128), 256, 0, stream>>>(av_bf, wo_bf, DMODEL, e5);
}

// Round 13
// 446.239 us; speedup vs baseline: 1.0352x; 1.0346x over previous
//
#include <hip/hip_runtime.h>
#include <hip/hip_bf16.h>
#include <cstdint>
#include <cstddef>

#define TLEN 2048
#define NB 2
#define DMODEL 1024
#define NH 16
#define NDH 64

typedef unsigned short ushortT;
typedef short bf16x8 __attribute__((ext_vector_type(8)));
typedef float f32x16 __attribute__((ext_vector_type(16)));

__device__ __forceinline__ ushortT f2bf(float f) {
  union { float f; unsigned int u; } x{f};
  unsigned int r = x.u + 0x7fff + ((x.u >> 16) & 1);   // RNE
  return (ushortT)(r >> 16);
}
__device__ __forceinline__ unsigned int pk2(float lo, float hi) {
  return ((unsigned int)f2bf(hi) << 16) | (unsigned int)f2bf(lo);
}
__device__ __forceinline__ float bf2f(ushortT u) {
  union { unsigned int u; float f; } x;
  x.u = ((unsigned int)u) << 16;
  return x.f;
}

__device__ __forceinline__ void gld_lds16(const void* g, void* l) {
  __builtin_amdgcn_global_load_lds(
      (const __attribute__((address_space(1))) unsigned int*)g,
      (__attribute__((address_space(3))) unsigned int*)l, 16, 0, 0);
}

// ---------------------------------------------------------------------------
// fused prologue: all f32->bf16 converts + mask floats + rk_ext zero row
// ---------------------------------------------------------------------------

__global__ __launch_bounds__(256) void cvt_all(
    const float* __restrict__ w, const float* __restrict__ wqkv,
    const float* __restrict__ r, const float* __restrict__ wr,
    const float* __restrict__ wo, ushortT* __restrict__ w_bf,
    ushortT* __restrict__ wqkv_bf, ushortT* __restrict__ r_bf,
    ushortT* __restrict__ wr_bf, ushortT* __restrict__ wo_bf,
    const int* __restrict__ mask, float* __restrict__ mfl,
    ushortT* __restrict__ rkE) {
  const size_t N0 = 1048576, N1 = N0 + 786432, N2 = N1 + 524288,
               N3 = N2 + 262144, N4 = N3 + 262144;
  size_t i = (size_t)blockIdx.x * 256 + threadIdx.x;
  const float* src; ushortT* dst; size_t off;
  if (i < N0)      { src = w;    dst = w_bf;    off = i; }
  else if (i < N1) { src = wqkv; dst = wqkv_bf; off = i - N0; }
  else if (i < N2) { src = r;    dst = r_bf;    off = i - N1; }
  else if (i < N3) { src = wr;   dst = wr_bf;   off = i - N2; }
  else if (i < N4) { src = wo;   dst = wo_bf;   off = i - N3; }
  else {
    size_t k = i - N4;
    if (k < 512) {                       // mask floats: 4 j per thread
      int j = (int)k * 4;
#pragma unroll
      for (int s = 0; s < 4; ++s) {
        mfl[j + s]        = mask[(size_t)(j + s) * NB]     ? 0.f : 1.f;
        mfl[TLEN + j + s] = mask[(size_t)(j + s) * NB + 1] ? 0.f : 1.f;
      }
    } else if (k < 512 + 256) {          // rk_ext zero row per head
      int ii = (int)k - 512; int h = ii >> 4, c = ii & 15;
      ushort4 z; z.x = 0; z.y = 0; z.z = 0; z.w = 0;
      *reinterpret_cast<ushort4*>(rkE + ((size_t)h * 4096 + 2048) * NDH + c * 4) = z;
    }
    return;
  }
  float4 v = reinterpret_cast<const float4*>(src)[off];
  ushort4 o;
  o.x = f2bf(v.x); o.y = f2bf(v.y); o.z = f2bf(v.z); o.w = f2bf(v.w);
  reinterpret_cast<ushort4*>(dst)[off] = o;
}

// ---------------------------------------------------------------------------
// bf16 MFMA GEMM (R10 form — unpipelined; the R11/R12 K-loop pipeline cost
// +17us via register pressure and was reverted)
// ---------------------------------------------------------------------------

template <typename Epi>
__global__ __launch_bounds__(256) void gemm_bf16(const ushortT* __restrict__ A,
                                                 const ushortT* __restrict__ B,
                                                 int K, Epi epi) {
  __shared__ ushortT Al[128 * 64];
  __shared__ ushortT Bl[128 * 64];
  const int tid = threadIdx.x;
  const int lane = tid & 63;
  const int wv = tid >> 6;
  const int wm = wv >> 1, wn = wv & 1;
  const int m0 = blockIdx.y * 128;
  const int n0 = blockIdx.x * 128;
  const int r32 = lane & 31;
  const int hh = lane >> 5;

  f32x16 acc[2][2];
#pragma unroll
  for (int i = 0; i < 2; ++i)
#pragma unroll
    for (int j = 0; j < 2; ++j)
#pragma unroll
      for (int e = 0; e < 16; ++e) acc[i][j][e] = 0.f;

  for (int k0 = 0; k0 < K; k0 += 64) {
#pragma unroll
    for (int it = 0; it < 4; ++it) {
      int idx = it * 256 + tid;          // 1024 chunks of 16B
      int r = idx >> 3, c = idx & 7;
      int gcol = k0 + ((c ^ (r & 7)) << 3);
      gld_lds16(A + (size_t)(m0 + r) * K + gcol, Al + idx * 8);
      gld_lds16(B + (size_t)(n0 + r) * K + gcol, Bl + idx * 8);
    }
    asm volatile("s_waitcnt vmcnt(0)");
    __syncthreads();
#pragma unroll
    for (int kc = 0; kc < 4; ++kc) {
      int lc = kc * 2 + hh;              // logical 16B chunk in row
      bf16x8 af[2], bfr[2];
#pragma unroll
      for (int f = 0; f < 2; ++f) {
        int ar = wm * 64 + f * 32 + r32;
        af[f] = *(const bf16x8*)(Al + ar * 64 + ((lc ^ (ar & 7)) << 3));
        int br = wn * 64 + f * 32 + r32;
        bfr[f] = *(const bf16x8*)(Bl + br * 64 + ((lc ^ (br & 7)) << 3));
      }
#pragma unroll
      for (int i = 0; i < 2; ++i)
#pragma unroll
        for (int j = 0; j < 2; ++j)
          acc[i][j] = __builtin_amdgcn_mfma_f32_32x32x16_bf16(af[i], bfr[j],
                                                              acc[i][j], 0, 0, 0);
    }
    __syncthreads();
  }

#pragma unroll
  for (int i = 0; i < 2; ++i)
#pragma unroll
    for (int j = 0; j < 2; ++j)
#pragma unroll
      for (int rg = 0; rg < 16; ++rg) {
        int m = m0 + wm * 64 + i * 32 + (rg & 3) + 8 * (rg >> 2) + 4 * hh;
        int n = n0 + wn * 64 + j * 32 + r32;
        epi.store(m, n, acc[i][j][rg]);
      }
}

struct EpiQKV {
  ushortT* qb; ushortT* kb; ushortT* vtb; const float* bias;
  __device__ void store(int m, int n, float val) const {
    int t = m >> 1, b = m & 1;
    int which = n >> 10;
    int h = (n >> 6) & (NH - 1);
    int dh = n & (NDH - 1);
    int bh = b * NH + h;
    if (which == 0)
      qb[((size_t)bh * TLEN + t) * NDH + dh] = f2bf(val + bias[(h << 6) | dh]);
    else if (which == 1)
      kb[((size_t)bh * TLEN + t) * NDH + dh] = f2bf(val);
    else
      vtb[((size_t)bh * NDH + dh) * TLEN + t] = f2bf(val);
  }
};

struct EpiRK {   // rk_ext: row m = rk[m] (m<=2047); row 2048 = 0 (cvt_all);
                 // row m = rk[m-2049] (m>=2049)
  ushortT* rkE;
  __device__ void store(int m, int n, float val) const {
    int h = n >> 6, dh = n & 63;
    ushortT v = f2bf(val);
    rkE[((size_t)h * 4096 + m) * NDH + dh] = v;
    if (m <= 2046)
      rkE[((size_t)h * 4096 + m + 2049) * NDH + dh] = v;
  }
};

struct EpiOut {
  float* out;
  __device__ void store(int m, int n, float val) const {
    out[(size_t)m * DMODEL + n] = val;
  }
};

// ---------------------------------------------------------------------------
// FAST attention (R10 form). Grid (32,32): blockIdx.y = bh, blockIdx.x = 64
// q rows; 2 waves/block. LDS-staged + single-buffer software pipeline with
// counted vmcnt(8).
// ---------------------------------------------------------------------------

__global__ __launch_bounds__(128) void attn_fast(
    const ushortT* __restrict__ qb, const ushortT* __restrict__ kb,
    const ushortT* __restrict__ vtb, const ushortT* __restrict__ rkE,
    const float* __restrict__ mfl, unsigned int* __restrict__ S,
    float* __restrict__ linv_g, ushortT* __restrict__ av_bf) {
  __shared__ float W[2][64][32];
  __shared__ ushortT KT[2048];   // [32 j][8 x 16B chunks], chunk c at c^(row&7)
  __shared__ ushortT VT[2048];   // [64 d][4 x 16B chunks], chunk c at c^(d&3)
  __shared__ ushortT RK[6144];   // [96 rows][8 chunks],    chunk c at c^(row&7)

  const int bh = blockIdx.y;
  const int b = bh >> 4, h = bh & 15;
  const int t = threadIdx.x >> 6;        // q-tile wave
  const int lane = threadIdx.x & 63;
  const int ql = lane & 31;
  const int hh = lane >> 5;
  const int Q0 = blockIdx.x * 64;
  const int q0 = Q0 + 32 * t;
  const int qg = q0 + ql;

  const ushortT* Qbh = qb + (size_t)bh * TLEN * NDH;
  const ushortT* Kbh = kb + (size_t)bh * TLEN * NDH;
  const ushortT* Vbh = vtb + (size_t)bh * NDH * TLEN;
  const ushortT* Rh  = rkE + (size_t)h * 4096 * NDH;
  const float* mflb  = mfl + (size_t)b * TLEN;
  unsigned int* Sb   = S + (size_t)bh * (TLEN / 2) * TLEN;
  float (*Wp)[32] = W[t];

  auto STAGE = [&](int j0) {
    const int U = 1984 + j0 - Q0;        // in [0, 4000]; U+96 <= 4096
#pragma unroll
    for (int i = 0; i < 6; ++i) {        // RK: 6 insts/wave
      int ci = (t * 6 + i) * 64 + lane;
      int row = ci >> 3, c = ci & 7;
      gld_lds16(Rh + (size_t)(U + row) * NDH + ((c ^ (row & 7)) << 3), RK + ci * 8);
    }
#pragma unroll
    for (int i = 0; i < 2; ++i) {        // KT + VT: 2+2 insts/wave
      int ci = (t * 2 + i) * 64 + lane;
      int row = ci >> 3, c = ci & 7;
      gld_lds16(Kbh + (size_t)(j0 + row) * NDH + ((c ^ (row & 7)) << 3), KT + ci * 8);
      int d = ci >> 2, c2 = ci & 3;
      gld_lds16(Vbh + (size_t)d * TLEN + j0 + ((c2 ^ (d & 3)) << 3), VT + ci * 8);
    }
  };

  bf16x8 Qf[4], Qs[4];
  {
    int r2 = min(qg + 1, TLEN - 1);
#pragma unroll
    for (int c = 0; c < 4; ++c) {
      Qf[c] = *(const bf16x8*)(Qbh + (size_t)qg * NDH + c * 16 + hh * 8);
      Qs[c] = *(const bf16x8*)(Qbh + (size_t)r2 * NDH + c * 16 + hh * 8);
    }
  }

  f32x16 pacc0, pacc1;
#pragma unroll
  for (int i = 0; i < 16; ++i) { pacc0[i] = 0.f; pacc1[i] = 0.f; }
  float l_acc = 0.f;

  // prologue: stage chunk 0, full drain
  STAGE(0);
  asm volatile("s_waitcnt vmcnt(0)");
  __builtin_amdgcn_s_barrier();

  for (int j0 = 0; j0 < TLEN; j0 += 32) {
    // current-chunk mask loads (oldest VMEM after stores -> cheap wait at exp)
    float4 mf4[4];
#pragma unroll
    for (int g = 0; g < 4; ++g)
      mf4[g] = *(const float4*)(mflb + j0 + 8 * g + 4 * hh);

    // ---- fragment ds_reads -> registers ----
    const int R1 = 32 * (1 - t) + ql;
    const int R2 = R1 + 32;
    bf16x8 a1[4], a2[4], ak[4];
#pragma unroll
    for (int c = 0; c < 4; ++c) {
      a1[c] = *(const bf16x8*)(RK + R1 * 64 + (((2 * c + hh) ^ (R1 & 7)) << 3));
      a2[c] = *(const bf16x8*)(RK + R2 * 64 + (((2 * c + hh) ^ (R2 & 7)) << 3));
      ak[c] = *(const bf16x8*)(KT + ql * 64 + (((2 * c + hh) ^ (ql & 7)) << 3));
    }
    bf16x8 vv0[2], vv1[2];
#pragma unroll
    for (int kh = 0; kh < 2; ++kh) {
      vv0[kh] = *(const bf16x8*)(VT + ql * 32 + (((2 * kh + hh) ^ (ql & 3)) << 3));
      vv1[kh] = *(const bf16x8*)(VT + (32 + ql) * 32 + (((2 * kh + hh) ^ (ql & 3)) << 3));
    }
    asm volatile("s_waitcnt lgkmcnt(0)");
    __builtin_amdgcn_s_barrier();        // tiles free to overwrite

    if (j0 + 32 < TLEN) STAGE(j0 + 32);  // async, hidden under compute below

    const bool t0w1 = (j0 <= q0);
    const bool t1w1 = (j0 < q0);

    // BD tile 1 -> W rows [0,32)
    f32x16 facc;
#pragma unroll
    for (int i = 0; i < 16; ++i) facc[i] = 0.f;
    __builtin_amdgcn_s_setprio(1);
#pragma unroll
    for (int c = 0; c < 4; ++c)
      facc = __builtin_amdgcn_mfma_f32_32x32x16_bf16(a1[c], t0w1 ? Qf[c] : Qs[c], facc, 0, 0, 0);
    __builtin_amdgcn_s_setprio(0);
#pragma unroll
    for (int r = 0; r < 16; ++r)
      Wp[(r & 3) + 8 * (r >> 2) + 4 * hh][ql] = facc[r];

    // BD tile 2 -> W rows [32,64)
#pragma unroll
    for (int i = 0; i < 16; ++i) facc[i] = 0.f;
    __builtin_amdgcn_s_setprio(1);
#pragma unroll
    for (int c = 0; c < 4; ++c)
      facc = __builtin_amdgcn_mfma_f32_32x32x16_bf16(a2[c], t1w1 ? Qf[c] : Qs[c], facc, 0, 0, 0);
    __builtin_amdgcn_s_setprio(0);
#pragma unroll
    for (int r = 0; r < 16; ++r)
      Wp[32 + (r & 3) + 8 * (r >> 2) + 4 * hh][ql] = facc[r];

    // AC tile (S^T)
    f32x16 cacc;
#pragma unroll
    for (int i = 0; i < 16; ++i) cacc[i] = 0.f;
    __builtin_amdgcn_s_setprio(1);
#pragma unroll
    for (int c = 0; c < 4; ++c)
      cacc = __builtin_amdgcn_mfma_f32_32x32x16_bf16(ak[c], Qf[c], cacc, 0, 0, 0);
    __builtin_amdgcn_s_setprio(0);

    float p[16];
#pragma unroll
    for (int r = 0; r < 16; ++r) {
      int jrow = (r & 3) + 8 * (r >> 2) + 4 * hh;
      float bd = Wp[jrow - ql + 31][ql];
      float sc = (cacc[r] + bd) * 0.125f;
      float mv = (&mf4[r >> 2].x)[r & 3];
      float pv = mv * __expf(sc);
      p[r] = pv;
      l_acc += pv;
    }

    unsigned int u[8];
#pragma unroll
    for (int i = 0; i < 8; ++i) u[i] = pk2(p[2 * i], p[2 * i + 1]);

    // coalesced transposed staging: S[bh][(j0+jrow)/2][qg]
#pragma unroll
    for (int i = 0; i < 8; ++i) {
      int r = 2 * i;
      int jrow = (r & 3) + 8 * (r >> 2) + 4 * hh;   // even
      Sb[(size_t)((j0 + jrow) >> 1) * TLEN + qg] = u[i];
    }

#pragma unroll
    for (int kh = 0; kh < 2; ++kh) {
      unsigned int t0 = (unsigned int)__shfl_xor((int)u[4 * kh + 0], 32);
      unsigned int t1 = (unsigned int)__shfl_xor((int)u[4 * kh + 1], 32);
      unsigned int t2 = (unsigned int)__shfl_xor((int)u[4 * kh + 2], 32);
      unsigned int t3 = (unsigned int)__shfl_xor((int)u[4 * kh + 3], 32);
      unsigned int fr[4];
      fr[0] = hh ? t2 : u[4 * kh + 0];
      fr[1] = hh ? t3 : u[4 * kh + 1];
      fr[2] = hh ? u[4 * kh + 2] : t0;
      fr[3] = hh ? u[4 * kh + 3] : t1;
      bf16x8 pa = *reinterpret_cast<bf16x8*>(fr);
      __builtin_amdgcn_s_setprio(1);
      pacc0 = __builtin_amdgcn_mfma_f32_32x32x16_bf16(pa, kh ? vv0[1] : vv0[0], pacc0, 0, 0, 0);
      pacc1 = __builtin_amdgcn_mfma_f32_32x32x16_bf16(pa, kh ? vv1[1] : vv1[0], pacc1, 0, 0, 0);
      __builtin_amdgcn_s_setprio(0);
    }

    if (j0 + 32 < TLEN) {
      // wait the 10 staging loads (oldest); S stores may stay in flight
      asm volatile("s_waitcnt vmcnt(8)");
      __builtin_amdgcn_s_barrier();      // next chunk's tiles visible
    }
  }

  // ---- wave-local epilogue ----
  float lt = l_acc + __shfl_xor(l_acc, 32);
  if (lane < 32) linv_g[(size_t)bh * TLEN + qg] = 1.0f / lt;
  float inv = 1.0f / lt;
#pragma unroll
  for (int r = 0; r < 16; ++r) {
    int qrow = (r & 3) + 8 * (r >> 2) + 4 * hh;
    float iv = __shfl(inv, qrow);
    size_t aoff = ((size_t)(q0 + qrow) * NB + b) * DMODEL + h * NDH;
    av_bf[aoff + ql] = f2bf(pacc0[r] * iv);
    av_bf[aoff + 32 + ql] = f2bf(pacc1[r] * iv);
  }
}

// ---------------------------------------------------------------------------
// Transpose-rescale: S[bh][jp][q] (bf16 j-pairs) -> prob[bh][q][j] f32 * 1/l.
// ---------------------------------------------------------------------------

__global__ __launch_bounds__(256) void rescale_t(const unsigned int* __restrict__ S,
                                                 const float* __restrict__ linv_g,
                                                 float* __restrict__ prob) {
  __shared__ unsigned int lds[64][65];
  __shared__ float liv[64];
  const int qt = blockIdx.x;   // 32 tiles of 64 q
  const int jt = blockIdx.y;   // 16 tiles of 64 jp (=128 j)
  const int bh = blockIdx.z;
  const int t = threadIdx.x;

  const unsigned int* Sb = S + ((size_t)bh * (TLEN / 2) + jt * 64) * TLEN + qt * 64;
  {
    int row = t >> 2, c0 = (t & 3) * 16;
#pragma unroll
    for (int k = 0; k < 4; ++k) {
      uint4 v = *reinterpret_cast<const uint4*>(Sb + (size_t)row * TLEN + c0 + k * 4);
      lds[row][c0 + k * 4 + 0] = v.x;
      lds[row][c0 + k * 4 + 1] = v.y;
      lds[row][c0 + k * 4 + 2] = v.z;
      lds[row][c0 + k * 4 + 3] = v.w;
    }
  }
  if (t < 64) liv[t] = linv_g[(size_t)bh * TLEN + qt * 64 + t];
  __syncthreads();

  float* P = prob + ((size_t)bh * TLEN + qt * 64) * TLEN + jt * 128;
#pragma unroll
  for (int k = 0; k < 8; ++k) {
    int idx = k * 256 + t;             // 2048 float4 = 64 rows x 32
    int row = idx >> 5, c4 = idx & 31;
    unsigned int u0 = lds[c4 * 2][row];
    unsigned int u1 = lds[c4 * 2 + 1][row];
    float iv = liv[row];
    float4 o;
    o.x = bf2f((ushortT)(u0 & 0xffff)) * iv;
    o.y = bf2f((ushortT)(u0 >> 16)) * iv;
    o.z = bf2f((ushortT)(u1 & 0xffff)) * iv;
    o.w = bf2f((ushortT)(u1 >> 16)) * iv;
    *reinterpret_cast<float4*>(P + (size_t)row * TLEN + c4 * 4) = o;
  }
}

// ---------------------------------------------------------------------------
// FALLBACK attention (unchanged): fused rescale, staging inside prob.
// Used only if d_ws is too small for the S buffer.
// ---------------------------------------------------------------------------

__global__ __launch_bounds__(256) void attn_fused(
    const ushortT* __restrict__ qb, const ushortT* __restrict__ kb,
    const ushortT* __restrict__ vtb, const ushortT* __restrict__ rkE,
    const float* __restrict__ mfl, float* __restrict__ prob,
    ushortT* __restrict__ av_bf) {
  __shared__ float W[4][64][32];
  __shared__ float sl[4][32];
  __shared__ float linv[64];

  const int bh = blockIdx.y;
  const int b = bh >> 4, h = bh & 15;
  const int wv = threadIdx.x >> 6;
  const int lane = threadIdx.x & 63;
  const int ql = lane & 31;
  const int hh = lane >> 5;
  const int qtile = wv & 1;
  const int jh = wv >> 1;
  const int q0 = blockIdx.x * 64 + qtile * 32;
  const int qg = q0 + ql;

  const ushortT* Qbh = qb + (size_t)bh * TLEN * NDH;
  const ushortT* Kbh = kb + (size_t)bh * TLEN * NDH;
  const ushortT* Vbh = vtb + (size_t)bh * NDH * TLEN;
  const ushortT* Rh  = rkE + (size_t)h * 4096 * NDH;
  const float* mflb  = mfl + (size_t)b * TLEN;
  float (*Wp)[32] = W[wv];

  bf16x8 Qf[4], Qs[4];
  {
    int r2 = min(qg + 1, TLEN - 1);
#pragma unroll
    for (int c = 0; c < 4; ++c) {
      Qf[c] = *(const bf16x8*)(Qbh + (size_t)qg * NDH + c * 16 + hh * 8);
      Qs[c] = *(const bf16x8*)(Qbh + (size_t)r2 * NDH + c * 16 + hh * 8);
    }
  }

  f32x16 pacc0, pacc1;
#pragma unroll
  for (int i = 0; i < 16; ++i) { pacc0[i] = 0.f; pacc1[i] = 0.f; }
  float l_acc = 0.f;

  ushortT* pbrow = (ushortT*)prob + ((size_t)bh * TLEN + qg) * 4096 + 2048;

  const int jbeg = jh * (TLEN / 2);
  const int jend = jbeg + (TLEN / 2);
  for (int j0 = jbeg; j0 < jend; j0 += 32) {
    const int base_t = 2016 + j0 - q0;
    const bool t0w1 = (j0 <= q0);
    const bool t1w1 = (j0 < q0);

    const ushortT* s0 = Rh + (size_t)(base_t + ql) * NDH + hh * 8;
    const ushortT* s1 = Rh + (size_t)(base_t + 32 + ql) * NDH + hh * 8;
    const ushortT* sk = Kbh + (size_t)(j0 + ql) * NDH + hh * 8;
    const ushortT* vrow0 = Vbh + (size_t)ql * TLEN + j0 + 8 * hh;
    const ushortT* vrow1 = Vbh + (size_t)(32 + ql) * TLEN + j0 + 8 * hh;
    bf16x8 rk0[4], rk1[4], kk[4];
#pragma unroll
    for (int c = 0; c < 4; ++c) {
      rk0[c] = *(const bf16x8*)(s0 + c * 16);
      rk1[c] = *(const bf16x8*)(s1 + c * 16);
      kk[c]  = *(const bf16x8*)(sk + c * 16);
    }
    bf16x8 v00 = *(const bf16x8*)(vrow0);
    bf16x8 v01 = *(const bf16x8*)(vrow0 + 16);
    bf16x8 v10 = *(const bf16x8*)(vrow1);
    bf16x8 v11 = *(const bf16x8*)(vrow1 + 16);
    float4 mf4[4];
#pragma unroll
    for (int g = 0; g < 4; ++g)
      mf4[g] = *(const float4*)(mflb + j0 + 8 * g + 4 * hh);

    f32x16 facc;
#pragma unroll
    for (int i = 0; i < 16; ++i) facc[i] = 0.f;
    __builtin_amdgcn_s_setprio(1);
#pragma unroll
    for (int c = 0; c < 4; ++c)
      facc = __builtin_amdgcn_mfma_f32_32x32x16_bf16(rk0[c], t0w1 ? Qf[c] : Qs[c], facc, 0, 0, 0);
    __builtin_amdgcn_s_setprio(0);
#pragma unroll
    for (int r = 0; r < 16; ++r)
      Wp[(r & 3) + 8 * (r >> 2) + 4 * hh][ql] = facc[r];

#pragma unroll
    for (int i = 0; i < 16; ++i) facc[i] = 0.f;
    __builtin_amdgcn_s_setprio(1);
#pragma unroll
    for (int c = 0; c < 4; ++c)
      facc = __builtin_amdgcn_mfma_f32_32x32x16_bf16(rk1[c], t1w1 ? Qf[c] : Qs[c], facc, 0, 0, 0);
    __builtin_amdgcn_s_setprio(0);
#pragma unroll
    for (int r = 0; r < 16; ++r)
      Wp[32 + (r & 3) + 8 * (r >> 2) + 4 * hh][ql] = facc[r];

    f32x16 cacc;
#pragma unroll
    for (int i = 0; i < 16; ++i) cacc[i] = 0.f;
    __builtin_amdgcn_s_setprio(1);
#pragma unroll
    for (int c = 0; c < 4; ++c)
      cacc = __builtin_amdgcn_mfma_f32_32x32x16_bf16(kk[c], Qf[c], cacc, 0, 0, 0);
    __builtin_amdgcn_s_setprio(0);

    float p[16];
#pragma unroll
    for (int r = 0; r < 16; ++r) {
      int jrow = (r & 3) + 8 * (r >> 2) + 4 * hh;
      float bd = Wp[jrow - ql + 31][ql];
      float sc = (cacc[r] + bd) * 0.125f;
      float mv = (&mf4[r >> 2].x)[r & 3];
      float pv = mv * __expf(sc);
      p[r] = pv;
      l_acc += pv;
    }

#pragma unroll
    for (int g = 0; g < 4; ++g) {
      uint2 st;
      st.x = pk2(p[4 * g + 0], p[4 * g + 1]);
      st.y = pk2(p[4 * g + 2], p[4 * g + 3]);
      *reinterpret_cast<uint2*>(pbrow + j0 + 8 * g + 4 * hh) = st;
    }

#pragma unroll
    for (int kh = 0; kh < 2; ++kh) {
      unsigned int u0 = pk2(p[8 * kh + 0], p[8 * kh + 1]);
      unsigned int u1 = pk2(p[8 * kh + 2], p[8 * kh + 3]);
      unsigned int u2 = pk2(p[8 * kh + 4], p[8 * kh + 5]);
      unsigned int u3 = pk2(p[8 * kh + 6], p[8 * kh + 7]);
      unsigned int t0 = (unsigned int)__shfl_xor((int)u0, 32);
      unsigned int t1 = (unsigned int)__shfl_xor((int)u1, 32);
      unsigned int t2 = (unsigned int)__shfl_xor((int)u2, 32);
      unsigned int t3 = (unsigned int)__shfl_xor((int)u3, 32);
      unsigned int fr[4];
      fr[0] = hh ? t2 : u0;
      fr[1] = hh ? t3 : u1;
      fr[2] = hh ? u2 : t0;
      fr[3] = hh ? u3 : t1;
      bf16x8 pa = *reinterpret_cast<bf16x8*>(fr);
      __builtin_amdgcn_s_setprio(1);
      pacc0 = __builtin_amdgcn_mfma_f32_32x32x16_bf16(pa, kh ? v01 : v00, pacc0, 0, 0, 0);
      pacc1 = __builtin_amdgcn_mfma_f32_32x32x16_bf16(pa, kh ? v11 : v10, pacc1, 0, 0, 0);
      __builtin_amdgcn_s_setprio(0);
    }
  }

#pragma unroll
  for (int r = 0; r < 16; ++r) {
    int qrow = (r & 3) + 8 * (r >> 2) + 4 * hh;
    Wp[qrow][ql] = pacc0[r];
    Wp[32 + qrow][ql] = pacc1[r];
  }
  float lh = l_acc + __shfl_xor(l_acc, 32);
  if (lane < 32) sl[wv][ql] = lh;
  __syncthreads();

  if (wv < 2) {
    if (lane < 32) {
      float lt = sl[wv][ql] + sl[wv + 2][ql];
      linv[wv * 32 + ql] = 1.0f / lt;
    }
#pragma unroll
    for (int r = 0; r < 16; ++r) {
      int qrow = (r & 3) + 8 * (r >> 2) + 4 * hh;
      float lt = sl[wv][qrow] + sl[wv + 2][qrow];
      float iv = 1.0f / lt;
      float s0v = W[wv][qrow][ql] + W[wv + 2][qrow][ql];
      float s1v = W[wv][32 + qrow][ql] + W[wv + 2][32 + qrow][ql];
      size_t aoff = ((size_t)(q0 + qrow) * NB + b) * DMODEL + h * NDH;
      av_bf[aoff + ql] = f2bf(s0v * iv);
      av_bf[aoff + 32 + ql] = f2bf(s1v * iv);
    }
  }
  __syncthreads();

  const ushortT* probus = (const ushortT*)prob;
  const int lr = lane >> 4;
  const int cg = lane & 15;
  for (int s = 0; s < 8; ++s) {
    const int rloc = qtile * 32 + s * 4 + lr;
    const int rowg = blockIdx.x * 64 + rloc;
    const size_t ub = ((size_t)bh * TLEN + rowg) * 4096 + 2048 + jh * 1024 + cg * 8;
    const size_t fb = ((size_t)bh * TLEN + rowg) * 2048 + jh * 1024 + cg * 8;
    uint4 a[8];
#pragma unroll
    for (int k = 0; k < 8; ++k)
      a[k] = *reinterpret_cast<const uint4*>(probus + ub + k * 128);
    const float iv = linv[rloc];
    __syncthreads();
#pragma unroll
    for (int k = 0; k < 8; ++k) {
      float4 o0, o1;
      o0.x = bf2f((ushortT)(a[k].x & 0xffff)) * iv;
      o0.y = bf2f((ushortT)(a[k].x >> 16)) * iv;
      o0.z = bf2f((ushortT)(a[k].y & 0xffff)) * iv;
      o0.w = bf2f((ushortT)(a[k].y >> 16)) * iv;
      o1.x = bf2f((ushortT)(a[k].z & 0xffff)) * iv;
      o1.y = bf2f((ushortT)(a[k].z >> 16)) * iv;
      o1.z = bf2f((ushortT)(a[k].w & 0xffff)) * iv;
      o1.w = bf2f((ushortT)(a[k].w >> 16)) * iv;
      *reinterpret_cast<float4*>(prob + fb + k * 128) = o0;
      *reinterpret_cast<float4*>(prob + fb + k * 128 + 4) = o1;
    }
  }
}

// ---------------------------------------------------------------------------

extern "C" void kernel_launch(void* const* d_in, const int* in_sizes, int n_in,
                              void* d_out, int out_size, void* d_ws, size_t ws_size,
                              hipStream_t stream) {
  const float* w      = (const float*)d_in[0];   // (T,B,D)
  const float* r      = (const float*)d_in[1];   // (T,D)
  const float* w_qkv  = (const float*)d_in[2];   // (3072,1024)
  const float* w_r    = (const float*)d_in[3];   // (1024,1024)
  const float* w_o    = (const float*)d_in[4];   // (1024,1024)
  const float* bias   = (const float*)d_in[5];   // (16,64)
  const int* mask     = (const int*)d_in[6];     // (T,B) int32

  float* out  = (float*)d_out;
  float* prob = out + (size_t)TLEN * NB * DMODEL;

  const size_t SZ = (size_t)NB * NH * TLEN * NDH;        // 4194304
  ushortT* w_bf    = (ushortT*)d_ws;
  ushortT* wqkv_bf = w_bf + (size_t)4096 * 1024;
  ushortT* r_bf    = wqkv_bf + (size_t)3072 * 1024;
  ushortT* wr_bf   = r_bf + (size_t)2048 * 1024;
  ushortT* wo_bf   = wr_bf + (size_t)1024 * 1024;
  ushortT* q_bf    = wo_bf + (size_t)1024 * 1024;
  ushortT* k_bf    = q_bf + SZ;
  ushortT* vt_bf   = k_bf + SZ;
  ushortT* rkE_bf  = vt_bf + SZ;                         // 16*4096*64
  ushortT* av_bf   = rkE_bf + (size_t)NH * 4096 * NDH;
  float* mfl       = (float*)(av_bf + SZ);
  float* linv_g    = mfl + (size_t)NB * TLEN;
  unsigned int* S  = (unsigned int*)(linv_g + (size_t)NB * NH * TLEN);
  const size_t need = (size_t)((char*)(S + (size_t)NB * NH * (TLEN / 2) * TLEN) -
                               (char*)d_ws);
  const bool fast = ws_size >= need;

  // fused prologue: 2883584 float4 converts + 768 tail threads
  cvt_all<<<dim3((2883584 + 768 + 255) / 256), 256, 0, stream>>>(
      w, w_qkv, r, w_r, w_o, w_bf, wqkv_bf, r_bf, wr_bf, wo_bf, mask, mfl, rkE_bf);

  EpiQKV e1{q_bf, k_bf, vt_bf, bias};
  gemm_bf16<EpiQKV><<<dim3(3072 / 128, 4096 / 128), 256, 0, stream>>>(w_bf, wqkv_bf, DMODEL, e1);
  EpiRK e2{rkE_bf};
  gemm_bf16<EpiRK><<<dim3(1024 / 128, 2048 / 128), 256, 0, stream>>>(r_bf, wr_bf, DMODEL, e2);

  if (fast) {
    attn_fast<<<dim3(32, 32), 128, 0, stream>>>(q_bf, k_bf, vt_bf, rkE_bf,
                                                mfl, S, linv_g, av_bf);
    rescale_t<<<dim3(32, 16, 32), 256, 0, stream>>>(S, linv_g, prob);
  } else {
    attn_fused<<<dim3(32, 32), 256, 0, stream>>>(q_bf, k_bf, vt_bf, rkE_bf,
                                                 mfl, prob, av_bf);
  }

  EpiOut e5{out};
  gemm_bf16<EpiOut><<<dim3(1024 / 128, 4096 / 128), 256, 0, stream>>>(av_bf, wo_bf, DMODEL, e5);
}